// Round 8
// baseline (263.720 us; speedup 1.0000x reference)
//
#include <hip/hip_runtime.h>
#include <hip/hip_bf16.h>
#include <math.h>

#define B_SZ 2048
#define L_SEQ 8
#define DMODEL 128
#define DSTATE 64
#define HEADDIM 32
#define DCONV 4
#define DINNER 256
#define NHEADS 8
#define DCONVCH 384   // DINNER + 2*DSTATE
#define DINPROJ 648   // 2*DINNER + 2*DSTATE + NHEADS
#define NPAD 656      // 41 * 16

typedef short bf16x8 __attribute__((ext_vector_type(8)));
typedef float floatx4 __attribute__((ext_vector_type(4)));

__device__ __forceinline__ float siluf(float x) {
    return x / (1.f + expf(-x));
}
__device__ __forceinline__ float bf2f(unsigned short h) {
    unsigned int u = ((unsigned int)h) << 16;
    return __builtin_bit_cast(float, u);
}
__device__ __forceinline__ unsigned short f2bf(float f) {
    __hip_bfloat16 b = __float2bfloat16(f);
    return __builtin_bit_cast(unsigned short, b);
}
__device__ __forceinline__ void unpack8(bf16x8 v, float* o) {
    #pragma unroll
    for (int j = 0; j < 8; ++j) o[j] = bf2f((unsigned short)v[j]);
}
// async global->LDS, 16B per lane; LDS dest = wave-uniform base + lane*16
__device__ __forceinline__ void gl_lds16(const unsigned short* g, unsigned short* l) {
    __builtin_amdgcn_global_load_lds(
        (const __attribute__((address_space(1))) unsigned int*)g,
        (__attribute__((address_space(3))) unsigned int*)l, 16, 0, 0);
}

// ---------------------------------------------------------------------------
// Merged prep (unchanged from R7).
// ---------------------------------------------------------------------------
__global__ __launch_bounds__(256) void prep_weights(
    const float* __restrict__ st_Win, const float* __restrict__ ex_Win,
    const float* __restrict__ st_Wout, const float* __restrict__ ex_Wout,
    const float* __restrict__ cs_Wq, const float* __restrict__ cs_Wk,
    const float* __restrict__ cs_Wv, const float* __restrict__ cs_Wo,
    const float* __restrict__ cx_Wq, const float* __restrict__ cx_Wk,
    const float* __restrict__ cx_Wv, const float* __restrict__ cx_Wo,
    const float* __restrict__ mlp_W,
    unsigned short* __restrict__ winT_st, unsigned short* __restrict__ winT_ex,
    unsigned short* __restrict__ woutT_st, unsigned short* __restrict__ woutT_ex,
    unsigned short* __restrict__ attnWT, unsigned short* __restrict__ mlpWt)
{
    __shared__ float tile[32][33];
    int blk = blockIdx.x;
    if (blk < 656) {
        const float* src = blk < 328 ? st_Win : ex_Win;
        unsigned short* dst = blk < 328 ? winT_st : winT_ex;
        int idx = (blk % 328) * 256 + threadIdx.x;
        if (idx >= NPAD * 128) return;
        int n = idx / 128, k = idx % 128;
        float v = (n < DINPROJ) ? src[k * DINPROJ + n] : 0.f;
        dst[idx] = f2bf(v);
    } else if (blk < 912) {
        const float* src = blk < 784 ? st_Wout : ex_Wout;
        unsigned short* dst = blk < 784 ? woutT_st : woutT_ex;
        int idx = ((blk - 656) % 128) * 256 + threadIdx.x;
        int n = idx / 256, k = idx % 256;
        dst[idx] = f2bf(src[k * 128 + n]);
    } else if (blk < 1424) {
        int b2 = blk - 912;
        int mat = b2 >> 6;
        const float* src = mat == 0 ? cs_Wq : mat == 1 ? cs_Wk : mat == 2 ? cs_Wv :
                           mat == 3 ? cs_Wo : mat == 4 ? cx_Wq : mat == 5 ? cx_Wk :
                           mat == 6 ? cx_Wv : cx_Wo;
        int e = (b2 & 63) * 256 + threadIdx.x;
        int n = e >> 7, k = e & 127;
        attnWT[mat * 16384 + n * 128 + k] = f2bf(src[k * 128 + n]);
    } else {
        int b2 = blk - 1424;
        int n0 = (b2 & 31) * 32, k0 = (b2 >> 5) * 32;
        const int tid = threadIdx.x;
        const int c = tid & 31, r0 = tid >> 5;
        for (int rr = r0; rr < 32; rr += 8)
            tile[rr][c] = mlp_W[(size_t)(k0 + rr) * 1024 + n0 + c];
        __syncthreads();
        for (int rr = r0; rr < 32; rr += 8)
            mlpWt[(size_t)(n0 + rr) * 2048 + k0 + c] = f2bf(tile[c][rr]);
    }
}

// ---------------------------------------------------------------------------
// Dual Mamba2 v3 (unchanged from R7).
// ---------------------------------------------------------------------------
#define LDK 136
#define LDZ 648
#define LDY 264
__global__ __launch_bounds__(256, 5) void mamba_dual(
    const float* __restrict__ u_ex, const float* __restrict__ u_st,
    const unsigned short* __restrict__ WinT_ex, const unsigned short* __restrict__ WinT_st,
    const float* __restrict__ convw_ex, const float* __restrict__ convw_st,
    const float* __restrict__ convb_ex, const float* __restrict__ convb_st,
    const float* __restrict__ dtb_ex, const float* __restrict__ dtb_st,
    const float* __restrict__ Alog_ex, const float* __restrict__ Alog_st,
    const float* __restrict__ Dp_ex, const float* __restrict__ Dp_st,
    const float* __restrict__ normw_ex, const float* __restrict__ normw_st,
    const unsigned short* __restrict__ WoutT_ex, const unsigned short* __restrict__ WoutT_st,
    unsigned short* __restrict__ out_ex, unsigned short* __restrict__ out_st)
{
    const int which = blockIdx.x >> 10;
    const float* u = which ? u_st : u_ex;
    const unsigned short* WinT = which ? WinT_st : WinT_ex;
    const float* convw = which ? convw_st : convw_ex;
    const float* convb = which ? convb_st : convb_ex;
    const float* dtb = which ? dtb_st : dtb_ex;
    const float* Alog = which ? Alog_st : Alog_ex;
    const float* Dp = which ? Dp_st : Dp_ex;
    const float* normw = which ? normw_st : normw_ex;
    const unsigned short* WoutT = which ? WoutT_st : WoutT_ex;
    unsigned short* outf = which ? out_st : out_ex;

    const int tid = threadIdx.x;
    const int lane = tid & 63;
    const int wave = tid >> 6;
    const int l15 = lane & 15;
    const int q8 = (lane >> 4) * 8;
    const int row0 = (lane >> 4) * 4;
    const int grow0 = (blockIdx.x & 1023) * 16;

    __shared__ __align__(16) unsigned short uA[16 * LDK];
    __shared__ __align__(16) unsigned short zx[16 * LDZ];
    __shared__ float dtraw[16][8];
    __shared__ float dtv[2][8][8];
    __shared__ float cum[2][8][8];
    __shared__ float Gm[2][8][8];
    __shared__ float rstd[16];
    float* coefp = (float*)uA;
    unsigned short* ybA = zx;

    for (int i = tid; i < 512; i += 256) {
        int r = i >> 5, k4 = (i & 31) * 4;
        float4 v = *(const float4*)(u + (size_t)(grow0 + r) * DMODEL + k4);
        ushort4 h;
        h.x = f2bf(v.x); h.y = f2bf(v.y); h.z = f2bf(v.z); h.w = f2bf(v.w);
        *(ushort4*)(uA + r * LDK + k4) = h;
    }
    __syncthreads();

    {
        bf16x8 af[4];
        #pragma unroll
        for (int kk = 0; kk < 4; ++kk)
            af[kk] = *(const bf16x8*)(uA + l15 * LDK + kk * 32 + q8);
        for (int nt = wave; nt < 41; nt += 4) {
            floatx4 acc = {0.f, 0.f, 0.f, 0.f};
            const unsigned short* bp = WinT + (size_t)(nt * 16 + l15) * 128 + q8;
            #pragma unroll
            for (int kk = 0; kk < 4; ++kk) {
                bf16x8 bf = *(const bf16x8*)(bp + kk * 32);
                acc = __builtin_amdgcn_mfma_f32_16x16x32_bf16(af[kk], bf, acc, 0, 0, 0);
            }
            if (nt == 40) {
                if (l15 < 8) {
                    #pragma unroll
                    for (int r = 0; r < 4; ++r)
                        dtraw[row0 + r][l15] = acc[r];
                }
            } else {
                #pragma unroll
                for (int r = 0; r < 4; ++r)
                    zx[(row0 + r) * LDZ + nt * 16 + l15] = f2bf(acc[r]);
            }
        }
    }
    __syncthreads();

    float cv[3][8];
    {
        #pragma unroll
        for (int it = 0; it < 3; ++it) {
            int i = tid + it * 256;
            int r = i / 48, g = i % 48;
            int c0 = g * 8;
            int l = r & 7, bloc = r >> 3;
            float s[8];
            float4 cb0 = *(const float4*)(convb + c0);
            float4 cb1 = *(const float4*)(convb + c0 + 4);
            s[0] = cb0.x; s[1] = cb0.y; s[2] = cb0.z; s[3] = cb0.w;
            s[4] = cb1.x; s[5] = cb1.y; s[6] = cb1.z; s[7] = cb1.w;
            #pragma unroll
            for (int k = 0; k < DCONV; ++k) {
                int lp = l + k - (DCONV - 1);
                if (lp >= 0) {
                    bf16x8 v = *(const bf16x8*)(zx + (bloc * 8 + lp) * LDZ + 256 + c0);
                    float vf[8];
                    unpack8(v, vf);
                    float4 w0 = *(const float4*)(convw + k * DCONVCH + c0);
                    float4 w1 = *(const float4*)(convw + k * DCONVCH + c0 + 4);
                    s[0] += vf[0] * w0.x; s[1] += vf[1] * w0.y;
                    s[2] += vf[2] * w0.z; s[3] += vf[3] * w0.w;
                    s[4] += vf[4] * w1.x; s[5] += vf[5] * w1.y;
                    s[6] += vf[6] * w1.z; s[7] += vf[7] * w1.w;
                }
            }
            #pragma unroll
            for (int j = 0; j < 8; ++j) cv[it][j] = siluf(s[j]);
        }
        if (tid < 128) {
            int r = tid >> 3, h = tid & 7;
            float v = dtraw[r][h] + dtb[h];
            dtv[r >> 3][r & 7][h] = (v > 20.f) ? v : log1pf(expf(v));
        }
    }
    __syncthreads();
    {
        #pragma unroll
        for (int it = 0; it < 3; ++it) {
            int i = tid + it * 256;
            int r = i / 48, c0 = (i % 48) * 8;
            bf16x8 o;
            #pragma unroll
            for (int j = 0; j < 8; ++j) o[j] = (short)f2bf(cv[it][j]);
            *(bf16x8*)(zx + r * LDZ + 256 + c0) = o;
        }
    }
    __syncthreads();

    if (tid < 128) {
        int bloc = tid >> 6, t = (tid >> 3) & 7, s = tid & 7;
        float a = 0.f;
        #pragma unroll
        for (int n = 0; n < DSTATE; n += 8) {
            bf16x8 bv = *(const bf16x8*)(zx + (bloc * 8 + s) * LDZ + 512 + n);
            bf16x8 cvv = *(const bf16x8*)(zx + (bloc * 8 + t) * LDZ + 576 + n);
            float bf_[8], cf_[8];
            unpack8(bv, bf_); unpack8(cvv, cf_);
            #pragma unroll
            for (int j = 0; j < 8; ++j) a += bf_[j] * cf_[j];
        }
        Gm[bloc][t][s] = a;
    } else if (tid < 144) {
        int j = tid - 128;
        int bloc = j >> 3, h = j & 7;
        float c = 0.f;
        for (int l = 0; l < L_SEQ; ++l) { c += dtv[bloc][l][h]; cum[bloc][l][h] = c; }
    }
    __syncthreads();

    for (int i = tid; i < 1024; i += 256) {
        int bloc = i >> 9, t = (i >> 6) & 7, s = (i >> 3) & 7, h = i & 7;
        float A = -expf(Alog[h]);
        coefp[i] = (s <= t)
            ? Gm[bloc][t][s] * expf(A * (cum[bloc][t][h] - cum[bloc][s][h])) * dtv[bloc][s][h]
            : 0.f;
    }
    __syncthreads();

    float yv[2][8];
    {
        float psum[2];
        #pragma unroll
        for (int it = 0; it < 2; ++it) {
            int i = tid + it * 256;
            int r = i >> 5, g = i & 31;
            int c0 = g * 8, h = g >> 2;
            int bloc = r >> 3, t = r & 7;
            float acc[8];
            {
                bf16x8 xv = *(const bf16x8*)(zx + r * LDZ + 256 + c0);
                float xf[8]; unpack8(xv, xf);
                float d = Dp[h];
                #pragma unroll
                for (int j = 0; j < 8; ++j) acc[j] = d * xf[j];
            }
            for (int s = 0; s <= t; ++s) {
                float cf = coefp[((bloc * 8 + t) * 8 + s) * 8 + h];
                bf16x8 xv = *(const bf16x8*)(zx + (bloc * 8 + s) * LDZ + 256 + c0);
                float xf[8]; unpack8(xv, xf);
                #pragma unroll
                for (int j = 0; j < 8; ++j) acc[j] += cf * xf[j];
            }
            bf16x8 zv = *(const bf16x8*)(zx + r * LDZ + c0);
            float zf[8]; unpack8(zv, zf);
            float p = 0.f;
            #pragma unroll
            for (int j = 0; j < 8; ++j) {
                float y = acc[j] * siluf(zf[j]);
                p += y * y;
                yv[it][j] = y;
            }
            psum[it] = p;
        }
        #pragma unroll
        for (int off = 16; off > 0; off >>= 1) {
            psum[0] += __shfl_down(psum[0], off, 32);
            psum[1] += __shfl_down(psum[1], off, 32);
        }
        if ((lane & 31) == 0) {
            int r = tid >> 5;
            rstd[r]     = rsqrtf(psum[0] * (1.f / DINNER) + 1e-5f);
            rstd[r + 8] = rsqrtf(psum[1] * (1.f / DINNER) + 1e-5f);
        }
    }
    __syncthreads();

    {
        #pragma unroll
        for (int it = 0; it < 2; ++it) {
            int i = tid + it * 256;
            int r = i >> 5, c0 = (i & 31) * 8;
            float rs = rstd[r];
            float4 w0 = *(const float4*)(normw + c0);
            float4 w1 = *(const float4*)(normw + c0 + 4);
            bf16x8 o;
            o[0] = (short)f2bf(yv[it][0] * rs * w0.x);
            o[1] = (short)f2bf(yv[it][1] * rs * w0.y);
            o[2] = (short)f2bf(yv[it][2] * rs * w0.z);
            o[3] = (short)f2bf(yv[it][3] * rs * w0.w);
            o[4] = (short)f2bf(yv[it][4] * rs * w1.x);
            o[5] = (short)f2bf(yv[it][5] * rs * w1.y);
            o[6] = (short)f2bf(yv[it][6] * rs * w1.z);
            o[7] = (short)f2bf(yv[it][7] * rs * w1.w);
            *(bf16x8*)(ybA + r * LDY + c0) = o;
        }
    }
    __syncthreads();

    {
        bf16x8 af[8];
        #pragma unroll
        for (int kk = 0; kk < 8; ++kk)
            af[kk] = *(const bf16x8*)(ybA + l15 * LDY + kk * 32 + q8);
        #pragma unroll
        for (int ni = 0; ni < 2; ++ni) {
            int nt = wave * 2 + ni;
            floatx4 acc = {0.f, 0.f, 0.f, 0.f};
            const unsigned short* bp = WoutT + (size_t)(nt * 16 + l15) * 256 + q8;
            #pragma unroll
            for (int kk = 0; kk < 8; ++kk) {
                bf16x8 bf = *(const bf16x8*)(bp + kk * 32);
                acc = __builtin_amdgcn_mfma_f32_16x16x32_bf16(af[kk], bf, acc, 0, 0, 0);
            }
            #pragma unroll
            for (int r = 0; r < 4; ++r)
                outf[(size_t)(grow0 + row0 + r) * DMODEL + nt * 16 + l15] = f2bf(acc[r]);
        }
    }
}

// ---------------------------------------------------------------------------
// Cross-attentions v3: pass-parallel. Waves 0-1 = pass 0 (cs), waves 2-3 =
// pass 1 (cx). 4 batches/block (M=32), grid 512. A-frags read directly from
// global (row-major matches A layout). attv aliases dead Qs. 4 barriers.
// ---------------------------------------------------------------------------
#define ASTR 136
#define VSTR 40
#define PSTR 40
__global__ __launch_bounds__(256, 2) void attn_kernel(
    const unsigned short* __restrict__ st_f,
    const unsigned short* __restrict__ exp_f,
    const unsigned short* __restrict__ WT,
    const float* __restrict__ cs_bq, const float* __restrict__ cs_bk,
    const float* __restrict__ cs_bv, const float* __restrict__ cs_bo,
    const float* __restrict__ cx_bq, const float* __restrict__ cx_bk,
    const float* __restrict__ cx_bv, const float* __restrict__ cx_bo,
    __hip_bfloat16* __restrict__ x)
{
    const int tid = threadIdx.x;
    const int lane = tid & 63, wave = tid >> 6;
    const int wp = wave >> 1;           // pass (0 = cs, 1 = cx)
    const int wv = wave & 1;            // wave-within-pass
    const int l15 = lane & 15;
    const int q8 = (lane >> 4) * 8;
    const int row0 = (lane >> 4) * 4;
    const int grow0 = blockIdx.x * 32;
    const int b0 = blockIdx.x * 4;
    const float scale = 0.08838834764831845f;

    __shared__ __align__(16) unsigned short QsA[2][32 * ASTR];  // Qs, later attv
    __shared__ __align__(16) unsigned short Ks[2][32 * ASTR];
    __shared__ __align__(16) unsigned short Vt[2][128 * VSTR];  // [chan][kvrow]
    __shared__ __align__(16) unsigned short P[2][32 * PSTR];
    __shared__ float Ss[2][32][33];

    const unsigned short* qg = wp ? exp_f : st_f;
    const unsigned short* kg = wp ? st_f : exp_f;
    const unsigned short* Wq = WT + (size_t)wp * 4 * 16384;
    const unsigned short* Wk = Wq + 16384;
    const unsigned short* Wv = Wq + 32768;
    const unsigned short* Wo = Wq + 49152;
    const float* bq = wp ? cx_bq : cs_bq;
    const float* bk = wp ? cx_bk : cs_bk;
    const float* bv = wp ? cx_bv : cs_bv;
    const float* bo = wp ? cx_bo : cs_bo;

    // --- Q/K/V projections; A-frags straight from global ---
    {
        bf16x8 aq[2][4], akv[2][4];
        #pragma unroll
        for (int mt = 0; mt < 2; ++mt)
            #pragma unroll
            for (int kk = 0; kk < 4; ++kk) {
                size_t off = (size_t)(grow0 + mt * 16 + l15) * 128 + kk * 32 + q8;
                aq[mt][kk]  = *(const bf16x8*)(qg + off);
                akv[mt][kk] = *(const bf16x8*)(kg + off);
            }
        #pragma unroll
        for (int ni = 0; ni < 4; ++ni) {
            int nc = (wv * 4 + ni) * 16 + l15;
            floatx4 aq0 = {0,0,0,0}, aq1 = {0,0,0,0};
            floatx4 ak0 = {0,0,0,0}, ak1 = {0,0,0,0};
            floatx4 av0 = {0,0,0,0}, av1 = {0,0,0,0};
            #pragma unroll
            for (int kk = 0; kk < 4; ++kk) {
                bf16x8 wqf = *(const bf16x8*)(Wq + (size_t)nc * 128 + kk * 32 + q8);
                bf16x8 wkf = *(const bf16x8*)(Wk + (size_t)nc * 128 + kk * 32 + q8);
                bf16x8 wvf = *(const bf16x8*)(Wv + (size_t)nc * 128 + kk * 32 + q8);
                aq0 = __builtin_amdgcn_mfma_f32_16x16x32_bf16(aq[0][kk],  wqf, aq0, 0, 0, 0);
                aq1 = __builtin_amdgcn_mfma_f32_16x16x32_bf16(aq[1][kk],  wqf, aq1, 0, 0, 0);
                ak0 = __builtin_amdgcn_mfma_f32_16x16x32_bf16(akv[0][kk], wkf, ak0, 0, 0, 0);
                ak1 = __builtin_amdgcn_mfma_f32_16x16x32_bf16(akv[1][kk], wkf, ak1, 0, 0, 0);
                av0 = __builtin_amdgcn_mfma_f32_16x16x32_bf16(akv[0][kk], wvf, av0, 0, 0, 0);
                av1 = __builtin_amdgcn_mfma_f32_16x16x32_bf16(akv[1][kk], wvf, av1, 0, 0, 0);
            }
            float bqv = bq[nc], bkv = bk[nc], bvv = bv[nc];
            #pragma unroll
            for (int r = 0; r < 4; ++r) {
                QsA[wp][(row0 + r) * ASTR + nc]      = f2bf(aq0[r] + bqv);
                QsA[wp][(16 + row0 + r) * ASTR + nc] = f2bf(aq1[r] + bqv);
                Ks[wp][(row0 + r) * ASTR + nc]       = f2bf(ak0[r] + bkv);
                Ks[wp][(16 + row0 + r) * ASTR + nc]  = f2bf(ak1[r] + bkv);
                Vt[wp][nc * VSTR + row0 + r]         = f2bf(av0[r] + bvv);
                Vt[wp][nc * VSTR + 16 + row0 + r]    = f2bf(av1[r] + bvv);
            }
        }
    }
    __syncthreads();

    // --- scores: S(32x32) = Q @ K^T; wave wv does m-row wv, both n-halves ---
    {
        #pragma unroll
        for (int ntS = 0; ntS < 2; ++ntS) {
            floatx4 s = {0,0,0,0};
            #pragma unroll
            for (int kk = 0; kk < 4; ++kk) {
                bf16x8 a = *(const bf16x8*)(QsA[wp] + (wv * 16 + l15) * ASTR + kk * 32 + q8);
                bf16x8 b = *(const bf16x8*)(Ks[wp] + (ntS * 16 + l15) * ASTR + kk * 32 + q8);
                s = __builtin_amdgcn_mfma_f32_16x16x32_bf16(a, b, s, 0, 0, 0);
            }
            #pragma unroll
            for (int r = 0; r < 4; ++r)
                Ss[wp][wv * 16 + row0 + r][ntS * 16 + l15] = s[r];
        }
    }
    __syncthreads();

    // --- softmax: 64 rows total (2 passes x 32), tid < 64 ---
    if (tid < 64) {
        int wp2 = tid >> 5, r = tid & 31, c0 = (r >> 3) * 8;
        float v[8], mx = -1e30f;
        #pragma unroll
        for (int c = 0; c < 8; ++c) {
            v[c] = Ss[wp2][r][c0 + c] * scale;
            mx = fmaxf(mx, v[c]);
        }
        float sum = 0.f;
        #pragma unroll
        for (int c = 0; c < 8; ++c) { v[c] = expf(v[c] - mx); sum += v[c]; }
        float inv = 1.f / sum;
        #pragma unroll
        for (int c = 0; c < 32; ++c) {
            float pv = (c >= c0 && c < c0 + 8) ? v[c - c0] * inv : 0.f;
            P[wp2][r * PSTR + c] = f2bf(pv);
        }
    }
    __syncthreads();

    // --- O = P(32x32) @ V(32x128); attv aliases QsA[wp] (dead) ---
    unsigned short* attv = QsA[wp];
    {
        #pragma unroll
        for (int ni = 0; ni < 4; ++ni) {
            int nc = (wv * 4 + ni) * 16 + l15;
            bf16x8 bv_ = *(const bf16x8*)(Vt[wp] + nc * VSTR + q8);
            #pragma unroll
            for (int mt = 0; mt < 2; ++mt) {
                bf16x8 ap = *(const bf16x8*)(P[wp] + (mt * 16 + l15) * PSTR + q8);
                floatx4 o = {0,0,0,0};
                o = __builtin_amdgcn_mfma_f32_16x16x32_bf16(ap, bv_, o, 0, 0, 0);
                #pragma unroll
                for (int r = 0; r < 4; ++r)
                    attv[(mt * 16 + row0 + r) * ASTR + nc] = f2bf(o[r]);
            }
        }
    }
    __syncthreads();

    // --- Wo projection -> x ---
    {
        bf16x8 ao[2][4];
        #pragma unroll
        for (int mt = 0; mt < 2; ++mt)
            #pragma unroll
            for (int kk = 0; kk < 4; ++kk)
                ao[mt][kk] = *(const bf16x8*)(attv + (mt * 16 + l15) * ASTR + kk * 32 + q8);
        #pragma unroll
        for (int ni = 0; ni < 4; ++ni) {
            int nc = (wv * 4 + ni) * 16 + l15;
            floatx4 a0 = {0,0,0,0}, a1 = {0,0,0,0};
            #pragma unroll
            for (int kk = 0; kk < 4; ++kk) {
                bf16x8 wof = *(const bf16x8*)(Wo + (size_t)nc * 128 + kk * 32 + q8);
                a0 = __builtin_amdgcn_mfma_f32_16x16x32_bf16(ao[0][kk], wof, a0, 0, 0, 0);
                a1 = __builtin_amdgcn_mfma_f32_16x16x32_bf16(ao[1][kk], wof, a1, 0, 0, 0);
            }
            float bov = bo[nc];
            #pragma unroll
            for (int r = 0; r < 4; ++r) {
                int rr0 = row0 + r;
                int rr1 = 16 + row0 + r;
                x[(size_t)(b0 + (rr0 >> 3)) * 2048 + (rr0 & 7) * 256 + wp * 128 + nc] =
                    __float2bfloat16(a0[r] + bov);
                x[(size_t)(b0 + (rr1 >> 3)) * 2048 + (rr1 & 7) * 256 + wp * 128 + nc] =
                    __float2bfloat16(a1[r] + bov);
            }
        }
    }
}

// ---------------------------------------------------------------------------
// MLP via MFMA v4: 64x64 tile, BK=64, double-buffered global_load_lds with
// XOR swizzle. Grid 512 = 2 blocks/CU; prefetch hides barrier drain.
// ---------------------------------------------------------------------------
__global__ __launch_bounds__(256, 2) void mlp_mfma(
    const unsigned short* __restrict__ X,   // [2048][2048] bf16
    const unsigned short* __restrict__ Wt,  // [1024][2048] bf16
    const float* __restrict__ bias,
    float* __restrict__ out)                // [2048][1024]
{
    __shared__ __align__(16) unsigned short As[2][64 * 64];  // 2 x 8 KB
    __shared__ __align__(16) unsigned short Bs[2][64 * 64];
    const int tid = threadIdx.x;
    const int wave = tid >> 6, lane = tid & 63;
    const int wm = (wave >> 1) * 32, wn = (wave & 1) * 32;
    const int bm = blockIdx.y * 64, bn = blockIdx.x * 64;
    const int l15 = lane & 15, q8 = (lane >> 4) * 8;

    const int c0i = tid, c1i = tid + 256;
    const int r0s = c0i >> 3, c0s = ((c0i & 7) ^ (r0s & 7)) * 8;
    const int r1s = c1i >> 3, c1s = ((c1i & 7) ^ (r1s & 7)) * 8;
    const unsigned short* gA0 = X + (size_t)(bm + r0s) * 2048 + c0s;
    const unsigned short* gA1 = X + (size_t)(bm + r1s) * 2048 + c1s;
    const unsigned short* gB0 = Wt + (size_t)(bn + r0s) * 2048 + c0s;
    const unsigned short* gB1 = Wt + (size_t)(bn + r1s) * 2048 + c1s;

    floatx4 acc[2][2];
    #pragma unroll
    for (int i = 0; i < 2; ++i)
        #pragma unroll
        for (int j = 0; j < 2; ++j) acc[i][j] = (floatx4){0.f, 0.f, 0.f, 0.f};

    const int ra0 = wm + l15, ra1 = wm + 16 + l15;
    const int rb0 = wn + l15, rb1 = wn + 16 + l15;

    // prologue: fill buffer 0
    gl_lds16(gA0, As[0] + c0i * 8);
    gl_lds16(gA1, As[0] + c1i * 8);
    gl_lds16(gB0, Bs[0] + c0i * 8);
    gl_lds16(gB1, Bs[0] + c1i * 8);
    __syncthreads();

    for (int k0 = 0; k0 < 2048; k0 += 64) {
        const int cur = (k0 >> 6) & 1, nxt = cur ^ 1;
        if (k0 + 64 < 2048) {   // prefetch next tile FIRST (overlaps compute)
            gl_lds16(gA0 + k0 + 64, As[nxt] + c0i * 8);
            gl_lds16(gA1 + k0 + 64, As[nxt] + c1i * 8);
            gl_lds16(gB0 + k0 + 64, Bs[nxt] + c0i * 8);
            gl_lds16(gB1 + k0 + 64, Bs[nxt] + c1i * 8);
        }
        #pragma unroll
        for (int ks = 0; ks < 2; ++ks) {
            int xx = ks * 4 + (q8 >> 3);
            bf16x8 a0 = *(const bf16x8*)(As[cur] + (ra0 * 8 + (xx ^ (ra0 & 7))) * 8);
            bf16x8 a1 = *(const bf16x8*)(As[cur] + (ra1 * 8 + (xx ^ (ra1 & 7))) * 8);
            bf16x8 b0 = *(const bf16x8*)(Bs[cur] + (rb0 * 8 + (xx ^ (rb0 & 7))) * 8);
            bf16x8 b1 = *(const bf16x8*)(Bs[cur] + (rb1 * 8 + (xx ^ (rb1 & 7))) * 8);
            acc[0][0] = __builtin_amdgcn_mfma_f32_16x16x32_bf16(a0, b0, acc[0][0], 0, 0, 0);
            acc[0][1] = __builtin_amdgcn_mfma_f32_16x16x32_bf16(a0, b1, acc[0][1], 0, 0, 0);
            acc[1][0] = __builtin_amdgcn_mfma_f32_16x16x32_bf16(a1, b0, acc[1][0], 0, 0, 0);
            acc[1][1] = __builtin_amdgcn_mfma_f32_16x16x32_bf16(a1, b1, acc[1][1], 0, 0, 0);
        }
        __syncthreads();   // cur reads done everywhere; nxt loads landed
    }

    const int row0 = (lane >> 4) * 4;
    #pragma unroll
    for (int j = 0; j < 2; ++j) {
        int col = bn + wn + j * 16 + l15;
        float bv = bias[col];
        #pragma unroll
        for (int r = 0; r < 4; ++r) {
            out[(size_t)(bm + wm + row0 + r) * 1024 + col] = acc[0][j][r] + bv;
            out[(size_t)(bm + wm + 16 + row0 + r) * 1024 + col] = acc[1][j][r] + bv;
        }
    }
}

extern "C" void kernel_launch(void* const* d_in, const int* in_sizes, int n_in,
                              void* d_out, int out_size, void* d_ws, size_t ws_size,
                              hipStream_t stream) {
    const float* st_feature = (const float*)d_in[0];
    const float* exp_feature = (const float*)d_in[1];
    const float* st_Win = (const float*)d_in[2];
    const float* st_convw = (const float*)d_in[3];
    const float* st_convb = (const float*)d_in[4];
    const float* st_dtb = (const float*)d_in[5];
    const float* st_Alog = (const float*)d_in[6];
    const float* st_D = (const float*)d_in[7];
    const float* st_normw = (const float*)d_in[8];
    const float* st_Wout = (const float*)d_in[9];
    const float* ex_Win = (const float*)d_in[10];
    const float* ex_convw = (const float*)d_in[11];
    const float* ex_convb = (const float*)d_in[12];
    const float* ex_dtb = (const float*)d_in[13];
    const float* ex_Alog = (const float*)d_in[14];
    const float* ex_D = (const float*)d_in[15];
    const float* ex_normw = (const float*)d_in[16];
    const float* ex_Wout = (const float*)d_in[17];
    const float* cx_Wq = (const float*)d_in[18]; const float* cx_bq = (const float*)d_in[19];
    const float* cx_Wk = (const float*)d_in[20]; const float* cx_bk = (const float*)d_in[21];
    const float* cx_Wv = (const float*)d_in[22]; const float* cx_bv = (const float*)d_in[23];
    const float* cx_Wo = (const float*)d_in[24]; const float* cx_bo = (const float*)d_in[25];
    const float* cs_Wq = (const float*)d_in[26]; const float* cs_bq = (const float*)d_in[27];
    const float* cs_Wk = (const float*)d_in[28]; const float* cs_bk = (const float*)d_in[29];
    const float* cs_Wv = (const float*)d_in[30]; const float* cs_bv = (const float*)d_in[31];
    const float* cs_Wo = (const float*)d_in[32]; const float* cs_bo = (const float*)d_in[33];
    const float* mlp_W = (const float*)d_in[34];
    const float* mlp_b = (const float*)d_in[35];

    unsigned short* wsu = (unsigned short*)d_ws;
    unsigned short* st_fb  = wsu;
    unsigned short* exp_fb = st_fb + (size_t)B_SZ * L_SEQ * DMODEL;
    unsigned short* xbuf   = exp_fb + (size_t)B_SZ * L_SEQ * DMODEL;
    unsigned short* wtbuf  = xbuf + (size_t)2048 * 2048;
    unsigned short* winT_st = wtbuf + (size_t)1024 * 2048;
    unsigned short* winT_ex = winT_st + (size_t)NPAD * 128;
    unsigned short* woutT_st = winT_ex + (size_t)NPAD * 128;
    unsigned short* woutT_ex = woutT_st + (size_t)128 * 256;
    unsigned short* attnWT  = woutT_ex + (size_t)128 * 256;

    prep_weights<<<3472, 256, 0, stream>>>(
        st_Win, ex_Win, st_Wout, ex_Wout,
        cs_Wq, cs_Wk, cs_Wv, cs_Wo, cx_Wq, cx_Wk, cx_Wv, cx_Wo, mlp_W,
        winT_st, winT_ex, woutT_st, woutT_ex, attnWT, wtbuf);
    mamba_dual<<<2048, 256, 0, stream>>>(
        exp_feature, st_feature, winT_ex, winT_st,
        ex_convw, st_convw, ex_convb, st_convb,
        ex_dtb, st_dtb, ex_Alog, st_Alog, ex_D, st_D,
        ex_normw, st_normw, woutT_ex, woutT_st,
        exp_fb, st_fb);
    attn_kernel<<<B_SZ / 4, 256, 0, stream>>>(st_fb, exp_fb, attnWT,
                                              cs_bq, cs_bk, cs_bv, cs_bo,
                                              cx_bq, cx_bk, cx_bv, cx_bo,
                                              (__hip_bfloat16*)xbuf);
    {
        dim3 g(1024 / 64, 2048 / 64);
        mlp_mfma<<<g, 256, 0, stream>>>(xbuf, wtbuf, mlp_b, (float*)d_out);
    }
}

// Round 9
// 260.914 us; speedup vs baseline: 1.0108x; 1.0108x over previous
//
#include <hip/hip_runtime.h>
#include <hip/hip_bf16.h>
#include <math.h>

#define B_SZ 2048
#define L_SEQ 8
#define DMODEL 128
#define DSTATE 64
#define HEADDIM 32
#define DCONV 4
#define DINNER 256
#define NHEADS 8
#define DCONVCH 384   // DINNER + 2*DSTATE
#define DINPROJ 648   // 2*DINNER + 2*DSTATE + NHEADS
#define NPAD 656      // 41 * 16

typedef short bf16x8 __attribute__((ext_vector_type(8)));
typedef float floatx4 __attribute__((ext_vector_type(4)));

__device__ __forceinline__ float siluf(float x) {
    return x / (1.f + expf(-x));
}
__device__ __forceinline__ float bf2f(unsigned short h) {
    unsigned int u = ((unsigned int)h) << 16;
    return __builtin_bit_cast(float, u);
}
__device__ __forceinline__ unsigned short f2bf(float f) {
    __hip_bfloat16 b = __float2bfloat16(f);
    return __builtin_bit_cast(unsigned short, b);
}
__device__ __forceinline__ void unpack8(bf16x8 v, float* o) {
    #pragma unroll
    for (int j = 0; j < 8; ++j) o[j] = bf2f((unsigned short)v[j]);
}
// async global->LDS, 16B per lane; LDS dest = wave-uniform base + lane*16
__device__ __forceinline__ void gl_lds16(const unsigned short* g, unsigned short* l) {
    __builtin_amdgcn_global_load_lds(
        (const __attribute__((address_space(1))) unsigned int*)g,
        (__attribute__((address_space(3))) unsigned int*)l, 16, 0, 0);
}

// ---------------------------------------------------------------------------
// Merged prep (unchanged).
// ---------------------------------------------------------------------------
__global__ __launch_bounds__(256) void prep_weights(
    const float* __restrict__ st_Win, const float* __restrict__ ex_Win,
    const float* __restrict__ st_Wout, const float* __restrict__ ex_Wout,
    const float* __restrict__ cs_Wq, const float* __restrict__ cs_Wk,
    const float* __restrict__ cs_Wv, const float* __restrict__ cs_Wo,
    const float* __restrict__ cx_Wq, const float* __restrict__ cx_Wk,
    const float* __restrict__ cx_Wv, const float* __restrict__ cx_Wo,
    const float* __restrict__ mlp_W,
    unsigned short* __restrict__ winT_st, unsigned short* __restrict__ winT_ex,
    unsigned short* __restrict__ woutT_st, unsigned short* __restrict__ woutT_ex,
    unsigned short* __restrict__ attnWT, unsigned short* __restrict__ mlpWt)
{
    __shared__ float tile[32][33];
    int blk = blockIdx.x;
    if (blk < 656) {
        const float* src = blk < 328 ? st_Win : ex_Win;
        unsigned short* dst = blk < 328 ? winT_st : winT_ex;
        int idx = (blk % 328) * 256 + threadIdx.x;
        if (idx >= NPAD * 128) return;
        int n = idx / 128, k = idx % 128;
        float v = (n < DINPROJ) ? src[k * DINPROJ + n] : 0.f;
        dst[idx] = f2bf(v);
    } else if (blk < 912) {
        const float* src = blk < 784 ? st_Wout : ex_Wout;
        unsigned short* dst = blk < 784 ? woutT_st : woutT_ex;
        int idx = ((blk - 656) % 128) * 256 + threadIdx.x;
        int n = idx / 256, k = idx % 256;
        dst[idx] = f2bf(src[k * 128 + n]);
    } else if (blk < 1424) {
        int b2 = blk - 912;
        int mat = b2 >> 6;
        const float* src = mat == 0 ? cs_Wq : mat == 1 ? cs_Wk : mat == 2 ? cs_Wv :
                           mat == 3 ? cs_Wo : mat == 4 ? cx_Wq : mat == 5 ? cx_Wk :
                           mat == 6 ? cx_Wv : cx_Wo;
        int e = (b2 & 63) * 256 + threadIdx.x;
        int n = e >> 7, k = e & 127;
        attnWT[mat * 16384 + n * 128 + k] = f2bf(src[k * 128 + n]);
    } else {
        int b2 = blk - 1424;
        int n0 = (b2 & 31) * 32, k0 = (b2 >> 5) * 32;
        const int tid = threadIdx.x;
        const int c = tid & 31, r0 = tid >> 5;
        for (int rr = r0; rr < 32; rr += 8)
            tile[rr][c] = mlp_W[(size_t)(k0 + rr) * 1024 + n0 + c];
        __syncthreads();
        for (int rr = r0; rr < 32; rr += 8)
            mlpWt[(size_t)(n0 + rr) * 2048 + k0 + c] = f2bf(tile[c][rr]);
    }
}

// ---------------------------------------------------------------------------
// Dual Mamba2 v3 (unchanged from R7/R8).
// ---------------------------------------------------------------------------
#define LDK 136
#define LDZ 648
#define LDY 264
__global__ __launch_bounds__(256, 5) void mamba_dual(
    const float* __restrict__ u_ex, const float* __restrict__ u_st,
    const unsigned short* __restrict__ WinT_ex, const unsigned short* __restrict__ WinT_st,
    const float* __restrict__ convw_ex, const float* __restrict__ convw_st,
    const float* __restrict__ convb_ex, const float* __restrict__ convb_st,
    const float* __restrict__ dtb_ex, const float* __restrict__ dtb_st,
    const float* __restrict__ Alog_ex, const float* __restrict__ Alog_st,
    const float* __restrict__ Dp_ex, const float* __restrict__ Dp_st,
    const float* __restrict__ normw_ex, const float* __restrict__ normw_st,
    const unsigned short* __restrict__ WoutT_ex, const unsigned short* __restrict__ WoutT_st,
    unsigned short* __restrict__ out_ex, unsigned short* __restrict__ out_st)
{
    const int which = blockIdx.x >> 10;
    const float* u = which ? u_st : u_ex;
    const unsigned short* WinT = which ? WinT_st : WinT_ex;
    const float* convw = which ? convw_st : convw_ex;
    const float* convb = which ? convb_st : convb_ex;
    const float* dtb = which ? dtb_st : dtb_ex;
    const float* Alog = which ? Alog_st : Alog_ex;
    const float* Dp = which ? Dp_st : Dp_ex;
    const float* normw = which ? normw_st : normw_ex;
    const unsigned short* WoutT = which ? WoutT_st : WoutT_ex;
    unsigned short* outf = which ? out_st : out_ex;

    const int tid = threadIdx.x;
    const int lane = tid & 63;
    const int wave = tid >> 6;
    const int l15 = lane & 15;
    const int q8 = (lane >> 4) * 8;
    const int row0 = (lane >> 4) * 4;
    const int grow0 = (blockIdx.x & 1023) * 16;

    __shared__ __align__(16) unsigned short uA[16 * LDK];
    __shared__ __align__(16) unsigned short zx[16 * LDZ];
    __shared__ float dtraw[16][8];
    __shared__ float dtv[2][8][8];
    __shared__ float cum[2][8][8];
    __shared__ float Gm[2][8][8];
    __shared__ float rstd[16];
    float* coefp = (float*)uA;
    unsigned short* ybA = zx;

    for (int i = tid; i < 512; i += 256) {
        int r = i >> 5, k4 = (i & 31) * 4;
        float4 v = *(const float4*)(u + (size_t)(grow0 + r) * DMODEL + k4);
        ushort4 h;
        h.x = f2bf(v.x); h.y = f2bf(v.y); h.z = f2bf(v.z); h.w = f2bf(v.w);
        *(ushort4*)(uA + r * LDK + k4) = h;
    }
    __syncthreads();

    {
        bf16x8 af[4];
        #pragma unroll
        for (int kk = 0; kk < 4; ++kk)
            af[kk] = *(const bf16x8*)(uA + l15 * LDK + kk * 32 + q8);
        for (int nt = wave; nt < 41; nt += 4) {
            floatx4 acc = {0.f, 0.f, 0.f, 0.f};
            const unsigned short* bp = WinT + (size_t)(nt * 16 + l15) * 128 + q8;
            #pragma unroll
            for (int kk = 0; kk < 4; ++kk) {
                bf16x8 bf = *(const bf16x8*)(bp + kk * 32);
                acc = __builtin_amdgcn_mfma_f32_16x16x32_bf16(af[kk], bf, acc, 0, 0, 0);
            }
            if (nt == 40) {
                if (l15 < 8) {
                    #pragma unroll
                    for (int r = 0; r < 4; ++r)
                        dtraw[row0 + r][l15] = acc[r];
                }
            } else {
                #pragma unroll
                for (int r = 0; r < 4; ++r)
                    zx[(row0 + r) * LDZ + nt * 16 + l15] = f2bf(acc[r]);
            }
        }
    }
    __syncthreads();

    float cv[3][8];
    {
        #pragma unroll
        for (int it = 0; it < 3; ++it) {
            int i = tid + it * 256;
            int r = i / 48, g = i % 48;
            int c0 = g * 8;
            int l = r & 7, bloc = r >> 3;
            float s[8];
            float4 cb0 = *(const float4*)(convb + c0);
            float4 cb1 = *(const float4*)(convb + c0 + 4);
            s[0] = cb0.x; s[1] = cb0.y; s[2] = cb0.z; s[3] = cb0.w;
            s[4] = cb1.x; s[5] = cb1.y; s[6] = cb1.z; s[7] = cb1.w;
            #pragma unroll
            for (int k = 0; k < DCONV; ++k) {
                int lp = l + k - (DCONV - 1);
                if (lp >= 0) {
                    bf16x8 v = *(const bf16x8*)(zx + (bloc * 8 + lp) * LDZ + 256 + c0);
                    float vf[8];
                    unpack8(v, vf);
                    float4 w0 = *(const float4*)(convw + k * DCONVCH + c0);
                    float4 w1 = *(const float4*)(convw + k * DCONVCH + c0 + 4);
                    s[0] += vf[0] * w0.x; s[1] += vf[1] * w0.y;
                    s[2] += vf[2] * w0.z; s[3] += vf[3] * w0.w;
                    s[4] += vf[4] * w1.x; s[5] += vf[5] * w1.y;
                    s[6] += vf[6] * w1.z; s[7] += vf[7] * w1.w;
                }
            }
            #pragma unroll
            for (int j = 0; j < 8; ++j) cv[it][j] = siluf(s[j]);
        }
        if (tid < 128) {
            int r = tid >> 3, h = tid & 7;
            float v = dtraw[r][h] + dtb[h];
            dtv[r >> 3][r & 7][h] = (v > 20.f) ? v : log1pf(expf(v));
        }
    }
    __syncthreads();
    {
        #pragma unroll
        for (int it = 0; it < 3; ++it) {
            int i = tid + it * 256;
            int r = i / 48, c0 = (i % 48) * 8;
            bf16x8 o;
            #pragma unroll
            for (int j = 0; j < 8; ++j) o[j] = (short)f2bf(cv[it][j]);
            *(bf16x8*)(zx + r * LDZ + 256 + c0) = o;
        }
    }
    __syncthreads();

    if (tid < 128) {
        int bloc = tid >> 6, t = (tid >> 3) & 7, s = tid & 7;
        float a = 0.f;
        #pragma unroll
        for (int n = 0; n < DSTATE; n += 8) {
            bf16x8 bv = *(const bf16x8*)(zx + (bloc * 8 + s) * LDZ + 512 + n);
            bf16x8 cvv = *(const bf16x8*)(zx + (bloc * 8 + t) * LDZ + 576 + n);
            float bf_[8], cf_[8];
            unpack8(bv, bf_); unpack8(cvv, cf_);
            #pragma unroll
            for (int j = 0; j < 8; ++j) a += bf_[j] * cf_[j];
        }
        Gm[bloc][t][s] = a;
    } else if (tid < 144) {
        int j = tid - 128;
        int bloc = j >> 3, h = j & 7;
        float c = 0.f;
        for (int l = 0; l < L_SEQ; ++l) { c += dtv[bloc][l][h]; cum[bloc][l][h] = c; }
    }
    __syncthreads();

    for (int i = tid; i < 1024; i += 256) {
        int bloc = i >> 9, t = (i >> 6) & 7, s = (i >> 3) & 7, h = i & 7;
        float A = -expf(Alog[h]);
        coefp[i] = (s <= t)
            ? Gm[bloc][t][s] * expf(A * (cum[bloc][t][h] - cum[bloc][s][h])) * dtv[bloc][s][h]
            : 0.f;
    }
    __syncthreads();

    float yv[2][8];
    {
        float psum[2];
        #pragma unroll
        for (int it = 0; it < 2; ++it) {
            int i = tid + it * 256;
            int r = i >> 5, g = i & 31;
            int c0 = g * 8, h = g >> 2;
            int bloc = r >> 3, t = r & 7;
            float acc[8];
            {
                bf16x8 xv = *(const bf16x8*)(zx + r * LDZ + 256 + c0);
                float xf[8]; unpack8(xv, xf);
                float d = Dp[h];
                #pragma unroll
                for (int j = 0; j < 8; ++j) acc[j] = d * xf[j];
            }
            for (int s = 0; s <= t; ++s) {
                float cf = coefp[((bloc * 8 + t) * 8 + s) * 8 + h];
                bf16x8 xv = *(const bf16x8*)(zx + (bloc * 8 + s) * LDZ + 256 + c0);
                float xf[8]; unpack8(xv, xf);
                #pragma unroll
                for (int j = 0; j < 8; ++j) acc[j] += cf * xf[j];
            }
            bf16x8 zv = *(const bf16x8*)(zx + r * LDZ + c0);
            float zf[8]; unpack8(zv, zf);
            float p = 0.f;
            #pragma unroll
            for (int j = 0; j < 8; ++j) {
                float y = acc[j] * siluf(zf[j]);
                p += y * y;
                yv[it][j] = y;
            }
            psum[it] = p;
        }
        #pragma unroll
        for (int off = 16; off > 0; off >>= 1) {
            psum[0] += __shfl_down(psum[0], off, 32);
            psum[1] += __shfl_down(psum[1], off, 32);
        }
        if ((lane & 31) == 0) {
            int r = tid >> 5;
            rstd[r]     = rsqrtf(psum[0] * (1.f / DINNER) + 1e-5f);
            rstd[r + 8] = rsqrtf(psum[1] * (1.f / DINNER) + 1e-5f);
        }
    }
    __syncthreads();

    {
        #pragma unroll
        for (int it = 0; it < 2; ++it) {
            int i = tid + it * 256;
            int r = i >> 5, c0 = (i & 31) * 8;
            float rs = rstd[r];
            float4 w0 = *(const float4*)(normw + c0);
            float4 w1 = *(const float4*)(normw + c0 + 4);
            bf16x8 o;
            o[0] = (short)f2bf(yv[it][0] * rs * w0.x);
            o[1] = (short)f2bf(yv[it][1] * rs * w0.y);
            o[2] = (short)f2bf(yv[it][2] * rs * w0.z);
            o[3] = (short)f2bf(yv[it][3] * rs * w0.w);
            o[4] = (short)f2bf(yv[it][4] * rs * w1.x);
            o[5] = (short)f2bf(yv[it][5] * rs * w1.y);
            o[6] = (short)f2bf(yv[it][6] * rs * w1.z);
            o[7] = (short)f2bf(yv[it][7] * rs * w1.w);
            *(bf16x8*)(ybA + r * LDY + c0) = o;
        }
    }
    __syncthreads();

    {
        bf16x8 af[8];
        #pragma unroll
        for (int kk = 0; kk < 8; ++kk)
            af[kk] = *(const bf16x8*)(ybA + l15 * LDY + kk * 32 + q8);
        #pragma unroll
        for (int ni = 0; ni < 2; ++ni) {
            int nt = wave * 2 + ni;
            floatx4 acc = {0.f, 0.f, 0.f, 0.f};
            const unsigned short* bp = WoutT + (size_t)(nt * 16 + l15) * 256 + q8;
            #pragma unroll
            for (int kk = 0; kk < 8; ++kk) {
                bf16x8 bf = *(const bf16x8*)(bp + kk * 32);
                acc = __builtin_amdgcn_mfma_f32_16x16x32_bf16(af[kk], bf, acc, 0, 0, 0);
            }
            #pragma unroll
            for (int r = 0; r < 4; ++r)
                outf[(size_t)(grow0 + row0 + r) * DMODEL + nt * 16 + l15] = f2bf(acc[r]);
        }
    }
}

// ---------------------------------------------------------------------------
// Cross-attentions v3: pass-parallel (unchanged from R8).
// ---------------------------------------------------------------------------
#define ASTR 136
#define VSTR 40
#define PSTR 40
__global__ __launch_bounds__(256, 2) void attn_kernel(
    const unsigned short* __restrict__ st_f,
    const unsigned short* __restrict__ exp_f,
    const unsigned short* __restrict__ WT,
    const float* __restrict__ cs_bq, const float* __restrict__ cs_bk,
    const float* __restrict__ cs_bv, const float* __restrict__ cs_bo,
    const float* __restrict__ cx_bq, const float* __restrict__ cx_bk,
    const float* __restrict__ cx_bv, const float* __restrict__ cx_bo,
    __hip_bfloat16* __restrict__ x)
{
    const int tid = threadIdx.x;
    const int lane = tid & 63, wave = tid >> 6;
    const int wp = wave >> 1;
    const int wv = wave & 1;
    const int l15 = lane & 15;
    const int q8 = (lane >> 4) * 8;
    const int row0 = (lane >> 4) * 4;
    const int grow0 = blockIdx.x * 32;
    const int b0 = blockIdx.x * 4;
    const float scale = 0.08838834764831845f;

    __shared__ __align__(16) unsigned short QsA[2][32 * ASTR];
    __shared__ __align__(16) unsigned short Ks[2][32 * ASTR];
    __shared__ __align__(16) unsigned short Vt[2][128 * VSTR];
    __shared__ __align__(16) unsigned short P[2][32 * PSTR];
    __shared__ float Ss[2][32][33];

    const unsigned short* qg = wp ? exp_f : st_f;
    const unsigned short* kg = wp ? st_f : exp_f;
    const unsigned short* Wq = WT + (size_t)wp * 4 * 16384;
    const unsigned short* Wk = Wq + 16384;
    const unsigned short* Wv = Wq + 32768;
    const unsigned short* Wo = Wq + 49152;
    const float* bq = wp ? cx_bq : cs_bq;
    const float* bk = wp ? cx_bk : cs_bk;
    const float* bv = wp ? cx_bv : cs_bv;
    const float* bo = wp ? cx_bo : cs_bo;

    {
        bf16x8 aq[2][4], akv[2][4];
        #pragma unroll
        for (int mt = 0; mt < 2; ++mt)
            #pragma unroll
            for (int kk = 0; kk < 4; ++kk) {
                size_t off = (size_t)(grow0 + mt * 16 + l15) * 128 + kk * 32 + q8;
                aq[mt][kk]  = *(const bf16x8*)(qg + off);
                akv[mt][kk] = *(const bf16x8*)(kg + off);
            }
        #pragma unroll
        for (int ni = 0; ni < 4; ++ni) {
            int nc = (wv * 4 + ni) * 16 + l15;
            floatx4 aq0 = {0,0,0,0}, aq1 = {0,0,0,0};
            floatx4 ak0 = {0,0,0,0}, ak1 = {0,0,0,0};
            floatx4 av0 = {0,0,0,0}, av1 = {0,0,0,0};
            #pragma unroll
            for (int kk = 0; kk < 4; ++kk) {
                bf16x8 wqf = *(const bf16x8*)(Wq + (size_t)nc * 128 + kk * 32 + q8);
                bf16x8 wkf = *(const bf16x8*)(Wk + (size_t)nc * 128 + kk * 32 + q8);
                bf16x8 wvf = *(const bf16x8*)(Wv + (size_t)nc * 128 + kk * 32 + q8);
                aq0 = __builtin_amdgcn_mfma_f32_16x16x32_bf16(aq[0][kk],  wqf, aq0, 0, 0, 0);
                aq1 = __builtin_amdgcn_mfma_f32_16x16x32_bf16(aq[1][kk],  wqf, aq1, 0, 0, 0);
                ak0 = __builtin_amdgcn_mfma_f32_16x16x32_bf16(akv[0][kk], wkf, ak0, 0, 0, 0);
                ak1 = __builtin_amdgcn_mfma_f32_16x16x32_bf16(akv[1][kk], wkf, ak1, 0, 0, 0);
                av0 = __builtin_amdgcn_mfma_f32_16x16x32_bf16(akv[0][kk], wvf, av0, 0, 0, 0);
                av1 = __builtin_amdgcn_mfma_f32_16x16x32_bf16(akv[1][kk], wvf, av1, 0, 0, 0);
            }
            float bqv = bq[nc], bkv = bk[nc], bvv = bv[nc];
            #pragma unroll
            for (int r = 0; r < 4; ++r) {
                QsA[wp][(row0 + r) * ASTR + nc]      = f2bf(aq0[r] + bqv);
                QsA[wp][(16 + row0 + r) * ASTR + nc] = f2bf(aq1[r] + bqv);
                Ks[wp][(row0 + r) * ASTR + nc]       = f2bf(ak0[r] + bkv);
                Ks[wp][(16 + row0 + r) * ASTR + nc]  = f2bf(ak1[r] + bkv);
                Vt[wp][nc * VSTR + row0 + r]         = f2bf(av0[r] + bvv);
                Vt[wp][nc * VSTR + 16 + row0 + r]    = f2bf(av1[r] + bvv);
            }
        }
    }
    __syncthreads();

    {
        #pragma unroll
        for (int ntS = 0; ntS < 2; ++ntS) {
            floatx4 s = {0,0,0,0};
            #pragma unroll
            for (int kk = 0; kk < 4; ++kk) {
                bf16x8 a = *(const bf16x8*)(QsA[wp] + (wv * 16 + l15) * ASTR + kk * 32 + q8);
                bf16x8 b = *(const bf16x8*)(Ks[wp] + (ntS * 16 + l15) * ASTR + kk * 32 + q8);
                s = __builtin_amdgcn_mfma_f32_16x16x32_bf16(a, b, s, 0, 0, 0);
            }
            #pragma unroll
            for (int r = 0; r < 4; ++r)
                Ss[wp][wv * 16 + row0 + r][ntS * 16 + l15] = s[r];
        }
    }
    __syncthreads();

    if (tid < 64) {
        int wp2 = tid >> 5, r = tid & 31, c0 = (r >> 3) * 8;
        float v[8], mx = -1e30f;
        #pragma unroll
        for (int c = 0; c < 8; ++c) {
            v[c] = Ss[wp2][r][c0 + c] * scale;
            mx = fmaxf(mx, v[c]);
        }
        float sum = 0.f;
        #pragma unroll
        for (int c = 0; c < 8; ++c) { v[c] = expf(v[c] - mx); sum += v[c]; }
        float inv = 1.f / sum;
        #pragma unroll
        for (int c = 0; c < 32; ++c) {
            float pv = (c >= c0 && c < c0 + 8) ? v[c - c0] * inv : 0.f;
            P[wp2][r * PSTR + c] = f2bf(pv);
        }
    }
    __syncthreads();

    unsigned short* attv = QsA[wp];
    {
        #pragma unroll
        for (int ni = 0; ni < 4; ++ni) {
            int nc = (wv * 4 + ni) * 16 + l15;
            bf16x8 bv_ = *(const bf16x8*)(Vt[wp] + nc * VSTR + q8);
            #pragma unroll
            for (int mt = 0; mt < 2; ++mt) {
                bf16x8 ap = *(const bf16x8*)(P[wp] + (mt * 16 + l15) * PSTR + q8);
                floatx4 o = {0,0,0,0};
                o = __builtin_amdgcn_mfma_f32_16x16x32_bf16(ap, bv_, o, 0, 0, 0);
                #pragma unroll
                for (int r = 0; r < 4; ++r)
                    attv[(mt * 16 + row0 + r) * ASTR + nc] = f2bf(o[r]);
            }
        }
    }
    __syncthreads();

    {
        bf16x8 ao[2][4];
        #pragma unroll
        for (int mt = 0; mt < 2; ++mt)
            #pragma unroll
            for (int kk = 0; kk < 4; ++kk)
                ao[mt][kk] = *(const bf16x8*)(attv + (mt * 16 + l15) * ASTR + kk * 32 + q8);
        #pragma unroll
        for (int ni = 0; ni < 4; ++ni) {
            int nc = (wv * 4 + ni) * 16 + l15;
            floatx4 a0 = {0,0,0,0}, a1 = {0,0,0,0};
            #pragma unroll
            for (int kk = 0; kk < 4; ++kk) {
                bf16x8 wof = *(const bf16x8*)(Wo + (size_t)nc * 128 + kk * 32 + q8);
                a0 = __builtin_amdgcn_mfma_f32_16x16x32_bf16(ao[0][kk], wof, a0, 0, 0, 0);
                a1 = __builtin_amdgcn_mfma_f32_16x16x32_bf16(ao[1][kk], wof, a1, 0, 0, 0);
            }
            float bov = bo[nc];
            #pragma unroll
            for (int r = 0; r < 4; ++r) {
                int rr0 = row0 + r;
                int rr1 = 16 + row0 + r;
                x[(size_t)(b0 + (rr0 >> 3)) * 2048 + (rr0 & 7) * 256 + wp * 128 + nc] =
                    __float2bfloat16(a0[r] + bov);
                x[(size_t)(b0 + (rr1 >> 3)) * 2048 + (rr1 & 7) * 256 + wp * 128 + nc] =
                    __float2bfloat16(a1[r] + bov);
            }
        }
    }
}

// ---------------------------------------------------------------------------
// MLP via MFMA v2 (RESTORED from R6 — best measured config): 64x64 tile,
// BK=64, single-buffered global_load_lds with XOR swizzle, grid 512 (2/CU).
// ---------------------------------------------------------------------------
__global__ __launch_bounds__(256, 2) void mlp_mfma(
    const unsigned short* __restrict__ X,   // [2048][2048] bf16
    const unsigned short* __restrict__ Wt,  // [1024][2048] bf16
    const float* __restrict__ bias,
    float* __restrict__ out)                // [2048][1024]
{
    __shared__ __align__(16) unsigned short As[64 * 64];
    __shared__ __align__(16) unsigned short Bs[64 * 64];
    const int tid = threadIdx.x;
    const int wave = tid >> 6, lane = tid & 63;
    const int wm = (wave >> 1) * 32, wn = (wave & 1) * 32;
    const int bm = blockIdx.y * 64, bn = blockIdx.x * 64;
    const int l15 = lane & 15, q8 = (lane >> 4) * 8;

    // staging: thread handles chunks tid and tid+256 (512 chunks per tile)
    const int c0i = tid, c1i = tid + 256;
    const int r0s = c0i >> 3, c0s = ((c0i & 7) ^ (r0s & 7)) * 8;
    const int r1s = c1i >> 3, c1s = ((c1i & 7) ^ (r1s & 7)) * 8;
    const unsigned short* gA0 = X + (size_t)(bm + r0s) * 2048 + c0s;
    const unsigned short* gA1 = X + (size_t)(bm + r1s) * 2048 + c1s;
    const unsigned short* gB0 = Wt + (size_t)(bn + r0s) * 2048 + c0s;
    const unsigned short* gB1 = Wt + (size_t)(bn + r1s) * 2048 + c1s;
    unsigned short* lA0 = As + c0i * 8;
    unsigned short* lA1 = As + c1i * 8;
    unsigned short* lB0 = Bs + c0i * 8;
    unsigned short* lB1 = Bs + c1i * 8;

    floatx4 acc[2][2];
    #pragma unroll
    for (int i = 0; i < 2; ++i)
        #pragma unroll
        for (int j = 0; j < 2; ++j) acc[i][j] = (floatx4){0.f, 0.f, 0.f, 0.f};

    const int ra0 = wm + l15, ra1 = wm + 16 + l15;
    const int rb0 = wn + l15, rb1 = wn + 16 + l15;

    for (int k0 = 0; k0 < 2048; k0 += 64) {
        __syncthreads();          // previous iteration's ds_reads done
        gl_lds16(gA0 + k0, lA0);
        gl_lds16(gA1 + k0, lA1);
        gl_lds16(gB0 + k0, lB0);
        gl_lds16(gB1 + k0, lB1);
        __syncthreads();          // drains vmcnt (loads landed in LDS)
        #pragma unroll
        for (int ks = 0; ks < 2; ++ks) {
            int xx = ks * 4 + (q8 >> 3);
            bf16x8 a0 = *(const bf16x8*)(As + (ra0 * 8 + (xx ^ (ra0 & 7))) * 8);
            bf16x8 a1 = *(const bf16x8*)(As + (ra1 * 8 + (xx ^ (ra1 & 7))) * 8);
            bf16x8 b0 = *(const bf16x8*)(Bs + (rb0 * 8 + (xx ^ (rb0 & 7))) * 8);
            bf16x8 b1 = *(const bf16x8*)(Bs + (rb1 * 8 + (xx ^ (rb1 & 7))) * 8);
            acc[0][0] = __builtin_amdgcn_mfma_f32_16x16x32_bf16(a0, b0, acc[0][0], 0, 0, 0);
            acc[0][1] = __builtin_amdgcn_mfma_f32_16x16x32_bf16(a0, b1, acc[0][1], 0, 0, 0);
            acc[1][0] = __builtin_amdgcn_mfma_f32_16x16x32_bf16(a1, b0, acc[1][0], 0, 0, 0);
            acc[1][1] = __builtin_amdgcn_mfma_f32_16x16x32_bf16(a1, b1, acc[1][1], 0, 0, 0);
        }
    }

    const int row0 = (lane >> 4) * 4;
    #pragma unroll
    for (int j = 0; j < 2; ++j) {
        int col = bn + wn + j * 16 + l15;
        float bv = bias[col];
        #pragma unroll
        for (int r = 0; r < 4; ++r) {
            out[(size_t)(bm + wm + row0 + r) * 1024 + col] = acc[0][j][r] + bv;
            out[(size_t)(bm + wm + 16 + row0 + r) * 1024 + col] = acc[1][j][r] + bv;
        }
    }
}

extern "C" void kernel_launch(void* const* d_in, const int* in_sizes, int n_in,
                              void* d_out, int out_size, void* d_ws, size_t ws_size,
                              hipStream_t stream) {
    const float* st_feature = (const float*)d_in[0];
    const float* exp_feature = (const float*)d_in[1];
    const float* st_Win = (const float*)d_in[2];
    const float* st_convw = (const float*)d_in[3];
    const float* st_convb = (const float*)d_in[4];
    const float* st_dtb = (const float*)d_in[5];
    const float* st_Alog = (const float*)d_in[6];
    const float* st_D = (const float*)d_in[7];
    const float* st_normw = (const float*)d_in[8];
    const float* st_Wout = (const float*)d_in[9];
    const float* ex_Win = (const float*)d_in[10];
    const float* ex_convw = (const float*)d_in[11];
    const float* ex_convb = (const float*)d_in[12];
    const float* ex_dtb = (const float*)d_in[13];
    const float* ex_Alog = (const float*)d_in[14];
    const float* ex_D = (const float*)d_in[15];
    const float* ex_normw = (const float*)d_in[16];
    const float* ex_Wout = (const float*)d_in[17];
    const float* cx_Wq = (const float*)d_in[18]; const float* cx_bq = (const float*)d_in[19];
    const float* cx_Wk = (const float*)d_in[20]; const float* cx_bk = (const float*)d_in[21];
    const float* cx_Wv = (const float*)d_in[22]; const float* cx_bv = (const float*)d_in[23];
    const float* cx_Wo = (const float*)d_in[24]; const float* cx_bo = (const float*)d_in[25];
    const float* cs_Wq = (const float*)d_in[26]; const float* cs_bq = (const float*)d_in[27];
    const float* cs_Wk = (const float*)d_in[28]; const float* cs_bk = (const float*)d_in[29];
    const float* cs_Wv = (const float*)d_in[30]; const float* cs_bv = (const float*)d_in[31];
    const float* cs_Wo = (const float*)d_in[32]; const float* cs_bo = (const float*)d_in[33];
    const float* mlp_W = (const float*)d_in[34];
    const float* mlp_b = (const float*)d_in[35];

    unsigned short* wsu = (unsigned short*)d_ws;
    unsigned short* st_fb  = wsu;
    unsigned short* exp_fb = st_fb + (size_t)B_SZ * L_SEQ * DMODEL;
    unsigned short* xbuf   = exp_fb + (size_t)B_SZ * L_SEQ * DMODEL;
    unsigned short* wtbuf  = xbuf + (size_t)2048 * 2048;
    unsigned short* winT_st = wtbuf + (size_t)1024 * 2048;
    unsigned short* winT_ex = winT_st + (size_t)NPAD * 128;
    unsigned short* woutT_st = winT_ex + (size_t)NPAD * 128;
    unsigned short* woutT_ex = woutT_st + (size_t)128 * 256;
    unsigned short* attnWT  = woutT_ex + (size_t)128 * 256;

    prep_weights<<<3472, 256, 0, stream>>>(
        st_Win, ex_Win, st_Wout, ex_Wout,
        cs_Wq, cs_Wk, cs_Wv, cs_Wo, cx_Wq, cx_Wk, cx_Wv, cx_Wo, mlp_W,
        winT_st, winT_ex, woutT_st, woutT_ex, attnWT, wtbuf);
    mamba_dual<<<2048, 256, 0, stream>>>(
        exp_feature, st_feature, winT_ex, winT_st,
        ex_convw, st_convw, ex_convb, st_convb,
        ex_dtb, st_dtb, ex_Alog, st_Alog, ex_D, st_D,
        ex_normw, st_normw, woutT_ex, woutT_st,
        exp_fb, st_fb);
    attn_kernel<<<B_SZ / 4, 256, 0, stream>>>(st_fb, exp_fb, attnWT,
                                              cs_bq, cs_bk, cs_bv, cs_bo,
                                              cx_bq, cx_bk, cx_bv, cx_bo,
                                              (__hip_bfloat16*)xbuf);
    {
        dim3 g(1024 / 64, 2048 / 64);
        mlp_mfma<<<g, 256, 0, stream>>>(xbuf, wtbuf, mlp_b, (float*)d_out);
    }
}

// Round 10
// 255.963 us; speedup vs baseline: 1.0303x; 1.0193x over previous
//
#include <hip/hip_runtime.h>
#include <hip/hip_bf16.h>
#include <math.h>

#define B_SZ 2048
#define L_SEQ 8
#define DMODEL 128
#define DSTATE 64
#define HEADDIM 32
#define DCONV 4
#define DINNER 256
#define NHEADS 8
#define DCONVCH 384   // DINNER + 2*DSTATE
#define DINPROJ 648   // 2*DINNER + 2*DSTATE + NHEADS
#define NPAD 656      // 41 * 16

typedef short bf16x8 __attribute__((ext_vector_type(8)));
typedef float floatx4 __attribute__((ext_vector_type(4)));

__device__ __forceinline__ float siluf(float x) {
    return x / (1.f + expf(-x));
}
__device__ __forceinline__ float bf2f(unsigned short h) {
    unsigned int u = ((unsigned int)h) << 16;
    return __builtin_bit_cast(float, u);
}
__device__ __forceinline__ unsigned short f2bf(float f) {
    __hip_bfloat16 b = __float2bfloat16(f);
    return __builtin_bit_cast(unsigned short, b);
}
__device__ __forceinline__ void unpack8(bf16x8 v, float* o) {
    #pragma unroll
    for (int j = 0; j < 8; ++j) o[j] = bf2f((unsigned short)v[j]);
}
// async global->LDS, 16B per lane; LDS dest = wave-uniform base + lane*16
__device__ __forceinline__ void gl_lds16(const unsigned short* g, unsigned short* l) {
    __builtin_amdgcn_global_load_lds(
        (const __attribute__((address_space(1))) unsigned int*)g,
        (__attribute__((address_space(3))) unsigned int*)l, 16, 0, 0);
}

// ---------------------------------------------------------------------------
// Merged prep (unchanged).
// ---------------------------------------------------------------------------
__global__ __launch_bounds__(256) void prep_weights(
    const float* __restrict__ st_Win, const float* __restrict__ ex_Win,
    const float* __restrict__ st_Wout, const float* __restrict__ ex_Wout,
    const float* __restrict__ cs_Wq, const float* __restrict__ cs_Wk,
    const float* __restrict__ cs_Wv, const float* __restrict__ cs_Wo,
    const float* __restrict__ cx_Wq, const float* __restrict__ cx_Wk,
    const float* __restrict__ cx_Wv, const float* __restrict__ cx_Wo,
    const float* __restrict__ mlp_W,
    unsigned short* __restrict__ winT_st, unsigned short* __restrict__ winT_ex,
    unsigned short* __restrict__ woutT_st, unsigned short* __restrict__ woutT_ex,
    unsigned short* __restrict__ attnWT, unsigned short* __restrict__ mlpWt)
{
    __shared__ float tile[32][33];
    int blk = blockIdx.x;
    if (blk < 656) {
        const float* src = blk < 328 ? st_Win : ex_Win;
        unsigned short* dst = blk < 328 ? winT_st : winT_ex;
        int idx = (blk % 328) * 256 + threadIdx.x;
        if (idx >= NPAD * 128) return;
        int n = idx / 128, k = idx % 128;
        float v = (n < DINPROJ) ? src[k * DINPROJ + n] : 0.f;
        dst[idx] = f2bf(v);
    } else if (blk < 912) {
        const float* src = blk < 784 ? st_Wout : ex_Wout;
        unsigned short* dst = blk < 784 ? woutT_st : woutT_ex;
        int idx = ((blk - 656) % 128) * 256 + threadIdx.x;
        int n = idx / 256, k = idx % 256;
        dst[idx] = f2bf(src[k * 128 + n]);
    } else if (blk < 1424) {
        int b2 = blk - 912;
        int mat = b2 >> 6;
        const float* src = mat == 0 ? cs_Wq : mat == 1 ? cs_Wk : mat == 2 ? cs_Wv :
                           mat == 3 ? cs_Wo : mat == 4 ? cx_Wq : mat == 5 ? cx_Wk :
                           mat == 6 ? cx_Wv : cx_Wo;
        int e = (b2 & 63) * 256 + threadIdx.x;
        int n = e >> 7, k = e & 127;
        attnWT[mat * 16384 + n * 128 + k] = f2bf(src[k * 128 + n]);
    } else {
        int b2 = blk - 1424;
        int n0 = (b2 & 31) * 32, k0 = (b2 >> 5) * 32;
        const int tid = threadIdx.x;
        const int c = tid & 31, r0 = tid >> 5;
        for (int rr = r0; rr < 32; rr += 8)
            tile[rr][c] = mlp_W[(size_t)(k0 + rr) * 1024 + n0 + c];
        __syncthreads();
        for (int rr = r0; rr < 32; rr += 8)
            mlpWt[(size_t)(n0 + rr) * 2048 + k0 + c] = f2bf(tile[c][rr]);
    }
}

// ---------------------------------------------------------------------------
// Dual Mamba2 v3 (unchanged).
// ---------------------------------------------------------------------------
#define LDK 136
#define LDZ 648
#define LDY 264
__global__ __launch_bounds__(256, 5) void mamba_dual(
    const float* __restrict__ u_ex, const float* __restrict__ u_st,
    const unsigned short* __restrict__ WinT_ex, const unsigned short* __restrict__ WinT_st,
    const float* __restrict__ convw_ex, const float* __restrict__ convw_st,
    const float* __restrict__ convb_ex, const float* __restrict__ convb_st,
    const float* __restrict__ dtb_ex, const float* __restrict__ dtb_st,
    const float* __restrict__ Alog_ex, const float* __restrict__ Alog_st,
    const float* __restrict__ Dp_ex, const float* __restrict__ Dp_st,
    const float* __restrict__ normw_ex, const float* __restrict__ normw_st,
    const unsigned short* __restrict__ WoutT_ex, const unsigned short* __restrict__ WoutT_st,
    unsigned short* __restrict__ out_ex, unsigned short* __restrict__ out_st)
{
    const int which = blockIdx.x >> 10;
    const float* u = which ? u_st : u_ex;
    const unsigned short* WinT = which ? WinT_st : WinT_ex;
    const float* convw = which ? convw_st : convw_ex;
    const float* convb = which ? convb_st : convb_ex;
    const float* dtb = which ? dtb_st : dtb_ex;
    const float* Alog = which ? Alog_st : Alog_ex;
    const float* Dp = which ? Dp_st : Dp_ex;
    const float* normw = which ? normw_st : normw_ex;
    const unsigned short* WoutT = which ? WoutT_st : WoutT_ex;
    unsigned short* outf = which ? out_st : out_ex;

    const int tid = threadIdx.x;
    const int lane = tid & 63;
    const int wave = tid >> 6;
    const int l15 = lane & 15;
    const int q8 = (lane >> 4) * 8;
    const int row0 = (lane >> 4) * 4;
    const int grow0 = (blockIdx.x & 1023) * 16;

    __shared__ __align__(16) unsigned short uA[16 * LDK];
    __shared__ __align__(16) unsigned short zx[16 * LDZ];
    __shared__ float dtraw[16][8];
    __shared__ float dtv[2][8][8];
    __shared__ float cum[2][8][8];
    __shared__ float Gm[2][8][8];
    __shared__ float rstd[16];
    float* coefp = (float*)uA;
    unsigned short* ybA = zx;

    for (int i = tid; i < 512; i += 256) {
        int r = i >> 5, k4 = (i & 31) * 4;
        float4 v = *(const float4*)(u + (size_t)(grow0 + r) * DMODEL + k4);
        ushort4 h;
        h.x = f2bf(v.x); h.y = f2bf(v.y); h.z = f2bf(v.z); h.w = f2bf(v.w);
        *(ushort4*)(uA + r * LDK + k4) = h;
    }
    __syncthreads();

    {
        bf16x8 af[4];
        #pragma unroll
        for (int kk = 0; kk < 4; ++kk)
            af[kk] = *(const bf16x8*)(uA + l15 * LDK + kk * 32 + q8);
        for (int nt = wave; nt < 41; nt += 4) {
            floatx4 acc = {0.f, 0.f, 0.f, 0.f};
            const unsigned short* bp = WinT + (size_t)(nt * 16 + l15) * 128 + q8;
            #pragma unroll
            for (int kk = 0; kk < 4; ++kk) {
                bf16x8 bf = *(const bf16x8*)(bp + kk * 32);
                acc = __builtin_amdgcn_mfma_f32_16x16x32_bf16(af[kk], bf, acc, 0, 0, 0);
            }
            if (nt == 40) {
                if (l15 < 8) {
                    #pragma unroll
                    for (int r = 0; r < 4; ++r)
                        dtraw[row0 + r][l15] = acc[r];
                }
            } else {
                #pragma unroll
                for (int r = 0; r < 4; ++r)
                    zx[(row0 + r) * LDZ + nt * 16 + l15] = f2bf(acc[r]);
            }
        }
    }
    __syncthreads();

    float cv[3][8];
    {
        #pragma unroll
        for (int it = 0; it < 3; ++it) {
            int i = tid + it * 256;
            int r = i / 48, g = i % 48;
            int c0 = g * 8;
            int l = r & 7, bloc = r >> 3;
            float s[8];
            float4 cb0 = *(const float4*)(convb + c0);
            float4 cb1 = *(const float4*)(convb + c0 + 4);
            s[0] = cb0.x; s[1] = cb0.y; s[2] = cb0.z; s[3] = cb0.w;
            s[4] = cb1.x; s[5] = cb1.y; s[6] = cb1.z; s[7] = cb1.w;
            #pragma unroll
            for (int k = 0; k < DCONV; ++k) {
                int lp = l + k - (DCONV - 1);
                if (lp >= 0) {
                    bf16x8 v = *(const bf16x8*)(zx + (bloc * 8 + lp) * LDZ + 256 + c0);
                    float vf[8];
                    unpack8(v, vf);
                    float4 w0 = *(const float4*)(convw + k * DCONVCH + c0);
                    float4 w1 = *(const float4*)(convw + k * DCONVCH + c0 + 4);
                    s[0] += vf[0] * w0.x; s[1] += vf[1] * w0.y;
                    s[2] += vf[2] * w0.z; s[3] += vf[3] * w0.w;
                    s[4] += vf[4] * w1.x; s[5] += vf[5] * w1.y;
                    s[6] += vf[6] * w1.z; s[7] += vf[7] * w1.w;
                }
            }
            #pragma unroll
            for (int j = 0; j < 8; ++j) cv[it][j] = siluf(s[j]);
        }
        if (tid < 128) {
            int r = tid >> 3, h = tid & 7;
            float v = dtraw[r][h] + dtb[h];
            dtv[r >> 3][r & 7][h] = (v > 20.f) ? v : log1pf(expf(v));
        }
    }
    __syncthreads();
    {
        #pragma unroll
        for (int it = 0; it < 3; ++it) {
            int i = tid + it * 256;
            int r = i / 48, c0 = (i % 48) * 8;
            bf16x8 o;
            #pragma unroll
            for (int j = 0; j < 8; ++j) o[j] = (short)f2bf(cv[it][j]);
            *(bf16x8*)(zx + r * LDZ + 256 + c0) = o;
        }
    }
    __syncthreads();

    if (tid < 128) {
        int bloc = tid >> 6, t = (tid >> 3) & 7, s = tid & 7;
        float a = 0.f;
        #pragma unroll
        for (int n = 0; n < DSTATE; n += 8) {
            bf16x8 bv = *(const bf16x8*)(zx + (bloc * 8 + s) * LDZ + 512 + n);
            bf16x8 cvv = *(const bf16x8*)(zx + (bloc * 8 + t) * LDZ + 576 + n);
            float bf_[8], cf_[8];
            unpack8(bv, bf_); unpack8(cvv, cf_);
            #pragma unroll
            for (int j = 0; j < 8; ++j) a += bf_[j] * cf_[j];
        }
        Gm[bloc][t][s] = a;
    } else if (tid < 144) {
        int j = tid - 128;
        int bloc = j >> 3, h = j & 7;
        float c = 0.f;
        for (int l = 0; l < L_SEQ; ++l) { c += dtv[bloc][l][h]; cum[bloc][l][h] = c; }
    }
    __syncthreads();

    for (int i = tid; i < 1024; i += 256) {
        int bloc = i >> 9, t = (i >> 6) & 7, s = (i >> 3) & 7, h = i & 7;
        float A = -expf(Alog[h]);
        coefp[i] = (s <= t)
            ? Gm[bloc][t][s] * expf(A * (cum[bloc][t][h] - cum[bloc][s][h])) * dtv[bloc][s][h]
            : 0.f;
    }
    __syncthreads();

    float yv[2][8];
    {
        float psum[2];
        #pragma unroll
        for (int it = 0; it < 2; ++it) {
            int i = tid + it * 256;
            int r = i >> 5, g = i & 31;
            int c0 = g * 8, h = g >> 2;
            int bloc = r >> 3, t = r & 7;
            float acc[8];
            {
                bf16x8 xv = *(const bf16x8*)(zx + r * LDZ + 256 + c0);
                float xf[8]; unpack8(xv, xf);
                float d = Dp[h];
                #pragma unroll
                for (int j = 0; j < 8; ++j) acc[j] = d * xf[j];
            }
            for (int s = 0; s <= t; ++s) {
                float cf = coefp[((bloc * 8 + t) * 8 + s) * 8 + h];
                bf16x8 xv = *(const bf16x8*)(zx + (bloc * 8 + s) * LDZ + 256 + c0);
                float xf[8]; unpack8(xv, xf);
                #pragma unroll
                for (int j = 0; j < 8; ++j) acc[j] += cf * xf[j];
            }
            bf16x8 zv = *(const bf16x8*)(zx + r * LDZ + c0);
            float zf[8]; unpack8(zv, zf);
            float p = 0.f;
            #pragma unroll
            for (int j = 0; j < 8; ++j) {
                float y = acc[j] * siluf(zf[j]);
                p += y * y;
                yv[it][j] = y;
            }
            psum[it] = p;
        }
        #pragma unroll
        for (int off = 16; off > 0; off >>= 1) {
            psum[0] += __shfl_down(psum[0], off, 32);
            psum[1] += __shfl_down(psum[1], off, 32);
        }
        if ((lane & 31) == 0) {
            int r = tid >> 5;
            rstd[r]     = rsqrtf(psum[0] * (1.f / DINNER) + 1e-5f);
            rstd[r + 8] = rsqrtf(psum[1] * (1.f / DINNER) + 1e-5f);
        }
    }
    __syncthreads();

    {
        #pragma unroll
        for (int it = 0; it < 2; ++it) {
            int i = tid + it * 256;
            int r = i >> 5, c0 = (i & 31) * 8;
            float rs = rstd[r];
            float4 w0 = *(const float4*)(normw + c0);
            float4 w1 = *(const float4*)(normw + c0 + 4);
            bf16x8 o;
            o[0] = (short)f2bf(yv[it][0] * rs * w0.x);
            o[1] = (short)f2bf(yv[it][1] * rs * w0.y);
            o[2] = (short)f2bf(yv[it][2] * rs * w0.z);
            o[3] = (short)f2bf(yv[it][3] * rs * w0.w);
            o[4] = (short)f2bf(yv[it][4] * rs * w1.x);
            o[5] = (short)f2bf(yv[it][5] * rs * w1.y);
            o[6] = (short)f2bf(yv[it][6] * rs * w1.z);
            o[7] = (short)f2bf(yv[it][7] * rs * w1.w);
            *(bf16x8*)(ybA + r * LDY + c0) = o;
        }
    }
    __syncthreads();

    {
        bf16x8 af[8];
        #pragma unroll
        for (int kk = 0; kk < 8; ++kk)
            af[kk] = *(const bf16x8*)(ybA + l15 * LDY + kk * 32 + q8);
        #pragma unroll
        for (int ni = 0; ni < 2; ++ni) {
            int nt = wave * 2 + ni;
            floatx4 acc = {0.f, 0.f, 0.f, 0.f};
            const unsigned short* bp = WoutT + (size_t)(nt * 16 + l15) * 256 + q8;
            #pragma unroll
            for (int kk = 0; kk < 8; ++kk) {
                bf16x8 bf = *(const bf16x8*)(bp + kk * 32);
                acc = __builtin_amdgcn_mfma_f32_16x16x32_bf16(af[kk], bf, acc, 0, 0, 0);
            }
            #pragma unroll
            for (int r = 0; r < 4; ++r)
                outf[(size_t)(grow0 + row0 + r) * DMODEL + nt * 16 + l15] = f2bf(acc[r]);
        }
    }
}

// ---------------------------------------------------------------------------
// Cross-attentions v2 (RESTORED from R6 — best measured config):
// 4 batches/block (M=32), staged features, sequential passes, grid 512.
// ---------------------------------------------------------------------------
#define ASTR 136
#define VSTR 40
#define PSTR 40
__global__ __launch_bounds__(256, 2) void attn_kernel(
    const unsigned short* __restrict__ st_f,
    const unsigned short* __restrict__ exp_f,
    const unsigned short* __restrict__ WT,
    const float* __restrict__ cs_bq, const float* __restrict__ cs_bk,
    const float* __restrict__ cs_bv, const float* __restrict__ cs_bo,
    const float* __restrict__ cx_bq, const float* __restrict__ cx_bk,
    const float* __restrict__ cx_bv, const float* __restrict__ cx_bo,
    __hip_bfloat16* __restrict__ x)
{
    const int tid = threadIdx.x;
    const int lane = tid & 63, wave = tid >> 6;
    const int l15 = lane & 15;
    const int q8 = (lane >> 4) * 8;
    const int row0 = (lane >> 4) * 4;
    const int grow0 = blockIdx.x * 32;
    const int b0 = blockIdx.x * 4;
    const float scale = 0.08838834764831845f;

    __shared__ __align__(16) unsigned short stf[32 * ASTR];
    __shared__ __align__(16) unsigned short exf[32 * ASTR];
    __shared__ __align__(16) unsigned short Qs[32 * ASTR];
    __shared__ __align__(16) unsigned short Ks[32 * ASTR];
    __shared__ __align__(16) unsigned short attv[32 * ASTR];
    __shared__ __align__(16) unsigned short Vt[128 * VSTR];  // [chan][kvrow 0..31]
    __shared__ __align__(16) unsigned short P[32 * PSTR];
    __shared__ float Ss[32][33];

    #pragma unroll
    for (int it = 0; it < 2; ++it) {
        int i = tid + it * 256;
        int r = i >> 4, c8 = (i & 15) * 8;
        *(uint4*)(stf + r * ASTR + c8) = *(const uint4*)(st_f + (size_t)(grow0 + r) * 128 + c8);
        *(uint4*)(exf + r * ASTR + c8) = *(const uint4*)(exp_f + (size_t)(grow0 + r) * 128 + c8);
    }
    __syncthreads();

    #pragma unroll
    for (int pass = 0; pass < 2; ++pass) {
        const unsigned short* qsrc = pass ? exf : stf;
        const unsigned short* kvsrc = pass ? stf : exf;
        const unsigned short* Wq = WT + (size_t)pass * 4 * 16384;
        const unsigned short* Wk = Wq + 16384;
        const unsigned short* Wv = Wq + 32768;
        const unsigned short* Wo = Wq + 49152;
        const float* bq = pass ? cx_bq : cs_bq;
        const float* bk = pass ? cx_bk : cs_bk;
        const float* bv = pass ? cx_bv : cs_bv;
        const float* bo = pass ? cx_bo : cs_bo;

        // --- Q/K/V projections (2 m-tiles x 2 n-tiles per wave) ---
        {
            bf16x8 aq[2][4], akv[2][4];
            #pragma unroll
            for (int mt = 0; mt < 2; ++mt)
                #pragma unroll
                for (int kk = 0; kk < 4; ++kk) {
                    aq[mt][kk]  = *(const bf16x8*)(qsrc  + (mt * 16 + l15) * ASTR + kk * 32 + q8);
                    akv[mt][kk] = *(const bf16x8*)(kvsrc + (mt * 16 + l15) * ASTR + kk * 32 + q8);
                }
            #pragma unroll
            for (int ni = 0; ni < 2; ++ni) {
                int nc = (wave * 2 + ni) * 16 + l15;
                floatx4 aq0 = {0,0,0,0}, aq1 = {0,0,0,0};
                floatx4 ak0 = {0,0,0,0}, ak1 = {0,0,0,0};
                floatx4 av0 = {0,0,0,0}, av1 = {0,0,0,0};
                #pragma unroll
                for (int kk = 0; kk < 4; ++kk) {
                    bf16x8 wqf = *(const bf16x8*)(Wq + (size_t)nc * 128 + kk * 32 + q8);
                    bf16x8 wkf = *(const bf16x8*)(Wk + (size_t)nc * 128 + kk * 32 + q8);
                    bf16x8 wvf = *(const bf16x8*)(Wv + (size_t)nc * 128 + kk * 32 + q8);
                    aq0 = __builtin_amdgcn_mfma_f32_16x16x32_bf16(aq[0][kk],  wqf, aq0, 0, 0, 0);
                    aq1 = __builtin_amdgcn_mfma_f32_16x16x32_bf16(aq[1][kk],  wqf, aq1, 0, 0, 0);
                    ak0 = __builtin_amdgcn_mfma_f32_16x16x32_bf16(akv[0][kk], wkf, ak0, 0, 0, 0);
                    ak1 = __builtin_amdgcn_mfma_f32_16x16x32_bf16(akv[1][kk], wkf, ak1, 0, 0, 0);
                    av0 = __builtin_amdgcn_mfma_f32_16x16x32_bf16(akv[0][kk], wvf, av0, 0, 0, 0);
                    av1 = __builtin_amdgcn_mfma_f32_16x16x32_bf16(akv[1][kk], wvf, av1, 0, 0, 0);
                }
                float bqv = bq[nc], bkv = bk[nc], bvv = bv[nc];
                #pragma unroll
                for (int r = 0; r < 4; ++r) {
                    Qs[(row0 + r) * ASTR + nc]      = f2bf(aq0[r] + bqv);
                    Qs[(16 + row0 + r) * ASTR + nc] = f2bf(aq1[r] + bqv);
                    Ks[(row0 + r) * ASTR + nc]      = f2bf(ak0[r] + bkv);
                    Ks[(16 + row0 + r) * ASTR + nc] = f2bf(ak1[r] + bkv);
                    Vt[nc * VSTR + row0 + r]        = f2bf(av0[r] + bvv);
                    Vt[nc * VSTR + 16 + row0 + r]   = f2bf(av1[r] + bvv);
                }
            }
        }
        __syncthreads();

        // --- scores: S(32x32) = Q @ K^T; wave w does tile (w>>1, w&1) ---
        {
            int mtS = wave >> 1, ntS = wave & 1;
            floatx4 s = {0,0,0,0};
            #pragma unroll
            for (int kk = 0; kk < 4; ++kk) {
                bf16x8 a = *(const bf16x8*)(Qs + (mtS * 16 + l15) * ASTR + kk * 32 + q8);
                bf16x8 b = *(const bf16x8*)(Ks + (ntS * 16 + l15) * ASTR + kk * 32 + q8);
                s = __builtin_amdgcn_mfma_f32_16x16x32_bf16(a, b, s, 0, 0, 0);
            }
            #pragma unroll
            for (int r = 0; r < 4; ++r)
                Ss[mtS * 16 + row0 + r][ntS * 16 + l15] = s[r];
        }
        __syncthreads();

        // --- softmax per q-row over its batch's 8 kv cols; build P ---
        if (tid < 32) {
            int r = tid, c0 = (r >> 3) * 8;
            float v[8], mx = -1e30f;
            #pragma unroll
            for (int c = 0; c < 8; ++c) {
                v[c] = Ss[r][c0 + c] * scale;
                mx = fmaxf(mx, v[c]);
            }
            float sum = 0.f;
            #pragma unroll
            for (int c = 0; c < 8; ++c) { v[c] = expf(v[c] - mx); sum += v[c]; }
            float inv = 1.f / sum;
            #pragma unroll
            for (int c = 0; c < 32; ++c) {
                float pv = (c >= c0 && c < c0 + 8) ? v[c - c0] * inv : 0.f;
                P[r * PSTR + c] = f2bf(pv);
            }
        }
        __syncthreads();

        // --- O = P(32x32) @ V(32x128): per wave 2 n-tiles x 2 m-tiles ---
        {
            #pragma unroll
            for (int ni = 0; ni < 2; ++ni) {
                int nc = (wave * 2 + ni) * 16 + l15;
                bf16x8 bv_ = *(const bf16x8*)(Vt + nc * VSTR + q8);
                #pragma unroll
                for (int mt = 0; mt < 2; ++mt) {
                    bf16x8 ap = *(const bf16x8*)(P + (mt * 16 + l15) * PSTR + q8);
                    floatx4 o = {0,0,0,0};
                    o = __builtin_amdgcn_mfma_f32_16x16x32_bf16(ap, bv_, o, 0, 0, 0);
                    #pragma unroll
                    for (int r = 0; r < 4; ++r)
                        attv[(mt * 16 + row0 + r) * ASTR + nc] = f2bf(o[r]);
                }
            }
        }
        __syncthreads();

        // --- Wo projection -> x ---
        {
            bf16x8 ao[2][4];
            #pragma unroll
            for (int mt = 0; mt < 2; ++mt)
                #pragma unroll
                for (int kk = 0; kk < 4; ++kk)
                    ao[mt][kk] = *(const bf16x8*)(attv + (mt * 16 + l15) * ASTR + kk * 32 + q8);
            #pragma unroll
            for (int ni = 0; ni < 2; ++ni) {
                int nc = (wave * 2 + ni) * 16 + l15;
                floatx4 a0 = {0,0,0,0}, a1 = {0,0,0,0};
                #pragma unroll
                for (int kk = 0; kk < 4; ++kk) {
                    bf16x8 wof = *(const bf16x8*)(Wo + (size_t)nc * 128 + kk * 32 + q8);
                    a0 = __builtin_amdgcn_mfma_f32_16x16x32_bf16(ao[0][kk], wof, a0, 0, 0, 0);
                    a1 = __builtin_amdgcn_mfma_f32_16x16x32_bf16(ao[1][kk], wof, a1, 0, 0, 0);
                }
                float bov = bo[nc];
                #pragma unroll
                for (int r = 0; r < 4; ++r) {
                    int rr0 = row0 + r;
                    int rr1 = 16 + row0 + r;
                    x[(size_t)(b0 + (rr0 >> 3)) * 2048 + (rr0 & 7) * 256 + pass * 128 + nc] =
                        __float2bfloat16(a0[r] + bov);
                    x[(size_t)(b0 + (rr1 >> 3)) * 2048 + (rr1 & 7) * 256 + pass * 128 + nc] =
                        __float2bfloat16(a1[r] + bov);
                }
            }
        }
        __syncthreads();
    }
}

// ---------------------------------------------------------------------------
// MLP via MFMA v2 (unchanged from R9): 64x64 tile, BK=64, single-buffered
// global_load_lds with XOR swizzle, grid 512 (2/CU).
// ---------------------------------------------------------------------------
__global__ __launch_bounds__(256, 2) void mlp_mfma(
    const unsigned short* __restrict__ X,   // [2048][2048] bf16
    const unsigned short* __restrict__ Wt,  // [1024][2048] bf16
    const float* __restrict__ bias,
    float* __restrict__ out)                // [2048][1024]
{
    __shared__ __align__(16) unsigned short As[64 * 64];
    __shared__ __align__(16) unsigned short Bs[64 * 64];
    const int tid = threadIdx.x;
    const int wave = tid >> 6, lane = tid & 63;
    const int wm = (wave >> 1) * 32, wn = (wave & 1) * 32;
    const int bm = blockIdx.y * 64, bn = blockIdx.x * 64;
    const int l15 = lane & 15, q8 = (lane >> 4) * 8;

    const int c0i = tid, c1i = tid + 256;
    const int r0s = c0i >> 3, c0s = ((c0i & 7) ^ (r0s & 7)) * 8;
    const int r1s = c1i >> 3, c1s = ((c1i & 7) ^ (r1s & 7)) * 8;
    const unsigned short* gA0 = X + (size_t)(bm + r0s) * 2048 + c0s;
    const unsigned short* gA1 = X + (size_t)(bm + r1s) * 2048 + c1s;
    const unsigned short* gB0 = Wt + (size_t)(bn + r0s) * 2048 + c0s;
    const unsigned short* gB1 = Wt + (size_t)(bn + r1s) * 2048 + c1s;
    unsigned short* lA0 = As + c0i * 8;
    unsigned short* lA1 = As + c1i * 8;
    unsigned short* lB0 = Bs + c0i * 8;
    unsigned short* lB1 = Bs + c1i * 8;

    floatx4 acc[2][2];
    #pragma unroll
    for (int i = 0; i < 2; ++i)
        #pragma unroll
        for (int j = 0; j < 2; ++j) acc[i][j] = (floatx4){0.f, 0.f, 0.f, 0.f};

    const int ra0 = wm + l15, ra1 = wm + 16 + l15;
    const int rb0 = wn + l15, rb1 = wn + 16 + l15;

    for (int k0 = 0; k0 < 2048; k0 += 64) {
        __syncthreads();
        gl_lds16(gA0 + k0, lA0);
        gl_lds16(gA1 + k0, lA1);
        gl_lds16(gB0 + k0, lB0);
        gl_lds16(gB1 + k0, lB1);
        __syncthreads();
        #pragma unroll
        for (int ks = 0; ks < 2; ++ks) {
            int xx = ks * 4 + (q8 >> 3);
            bf16x8 a0 = *(const bf16x8*)(As + (ra0 * 8 + (xx ^ (ra0 & 7))) * 8);
            bf16x8 a1 = *(const bf16x8*)(As + (ra1 * 8 + (xx ^ (ra1 & 7))) * 8);
            bf16x8 b0 = *(const bf16x8*)(Bs + (rb0 * 8 + (xx ^ (rb0 & 7))) * 8);
            bf16x8 b1 = *(const bf16x8*)(Bs + (rb1 * 8 + (xx ^ (rb1 & 7))) * 8);
            acc[0][0] = __builtin_amdgcn_mfma_f32_16x16x32_bf16(a0, b0, acc[0][0], 0, 0, 0);
            acc[0][1] = __builtin_amdgcn_mfma_f32_16x16x32_bf16(a0, b1, acc[0][1], 0, 0, 0);
            acc[1][0] = __builtin_amdgcn_mfma_f32_16x16x32_bf16(a1, b0, acc[1][0], 0, 0, 0);
            acc[1][1] = __builtin_amdgcn_mfma_f32_16x16x32_bf16(a1, b1, acc[1][1], 0, 0, 0);
        }
    }

    const int row0 = (lane >> 4) * 4;
    #pragma unroll
    for (int j = 0; j < 2; ++j) {
        int col = bn + wn + j * 16 + l15;
        float bv = bias[col];
        #pragma unroll
        for (int r = 0; r < 4; ++r) {
            out[(size_t)(bm + wm + row0 + r) * 1024 + col] = acc[0][j][r] + bv;
            out[(size_t)(bm + wm + 16 + row0 + r) * 1024 + col] = acc[1][j][r] + bv;
        }
    }
}

extern "C" void kernel_launch(void* const* d_in, const int* in_sizes, int n_in,
                              void* d_out, int out_size, void* d_ws, size_t ws_size,
                              hipStream_t stream) {
    const float* st_feature = (const float*)d_in[0];
    const float* exp_feature = (const float*)d_in[1];
    const float* st_Win = (const float*)d_in[2];
    const float* st_convw = (const float*)d_in[3];
    const float* st_convb = (const float*)d_in[4];
    const float* st_dtb = (const float*)d_in[5];
    const float* st_Alog = (const float*)d_in[6];
    const float* st_D = (const float*)d_in[7];
    const float* st_normw = (const float*)d_in[8];
    const float* st_Wout = (const float*)d_in[9];
    const float* ex_Win = (const float*)d_in[10];
    const float* ex_convw = (const float*)d_in[11];
    const float* ex_convb = (const float*)d_in[12];
    const float* ex_dtb = (const float*)d_in[13];
    const float* ex_Alog = (const float*)d_in[14];
    const float* ex_D = (const float*)d_in[15];
    const float* ex_normw = (const float*)d_in[16];
    const float* ex_Wout = (const float*)d_in[17];
    const float* cx_Wq = (const float*)d_in[18]; const float* cx_bq = (const float*)d_in[19];
    const float* cx_Wk = (const float*)d_in[20]; const float* cx_bk = (const float*)d_in[21];
    const float* cx_Wv = (const float*)d_in[22]; const float* cx_bv = (const float*)d_in[23];
    const float* cx_Wo = (const float*)d_in[24]; const float* cx_bo = (const float*)d_in[25];
    const float* cs_Wq = (const float*)d_in[26]; const float* cs_bq = (const float*)d_in[27];
    const float* cs_Wk = (const float*)d_in[28]; const float* cs_bk = (const float*)d_in[29];
    const float* cs_Wv = (const float*)d_in[30]; const float* cs_bv = (const float*)d_in[31];
    const float* cs_Wo = (const float*)d_in[32]; const float* cs_bo = (const float*)d_in[33];
    const float* mlp_W = (const float*)d_in[34];
    const float* mlp_b = (const float*)d_in[35];

    unsigned short* wsu = (unsigned short*)d_ws;
    unsigned short* st_fb  = wsu;
    unsigned short* exp_fb = st_fb + (size_t)B_SZ * L_SEQ * DMODEL;
    unsigned short* xbuf   = exp_fb + (size_t)B_SZ * L_SEQ * DMODEL;
    unsigned short* wtbuf  = xbuf + (size_t)2048 * 2048;
    unsigned short* winT_st = wtbuf + (size_t)1024 * 2048;
    unsigned short* winT_ex = winT_st + (size_t)NPAD * 128;
    unsigned short* woutT_st = winT_ex + (size_t)NPAD * 128;
    unsigned short* woutT_ex = woutT_st + (size_t)128 * 256;
    unsigned short* attnWT  = woutT_ex + (size_t)128 * 256;

    prep_weights<<<3472, 256, 0, stream>>>(
        st_Win, ex_Win, st_Wout, ex_Wout,
        cs_Wq, cs_Wk, cs_Wv, cs_Wo, cx_Wq, cx_Wk, cx_Wv, cx_Wo, mlp_W,
        winT_st, winT_ex, woutT_st, woutT_ex, attnWT, wtbuf);
    mamba_dual<<<2048, 256, 0, stream>>>(
        exp_feature, st_feature, winT_ex, winT_st,
        ex_convw, st_convw, ex_convb, st_convb,
        ex_dtb, st_dtb, ex_Alog, st_Alog, ex_D, st_D,
        ex_normw, st_normw, woutT_ex, woutT_st,
        exp_fb, st_fb);
    attn_kernel<<<B_SZ / 4, 256, 0, stream>>>(st_fb, exp_fb, attnWT,
                                              cs_bq, cs_bk, cs_bv, cs_bo,
                                              cx_bq, cx_bk, cx_bv, cx_bo,
                                              (__hip_bfloat16*)xbuf);
    {
        dim3 g(1024 / 64, 2048 / 64);
        mlp_mfma<<<g, 256, 0, stream>>>(xbuf, wtbuf, mlp_b, (float*)d_out);
    }
}